// Round 2
// baseline (2860.094 us; speedup 1.0000x reference)
//
#include <hip/hip_runtime.h>

// ============================================================================
// New_LinkNet GNN forward — fp32 with bf16 K/V staging.
// Round-2 changes vs round 1 (which died with a GPU memory fault):
//  - Peak workspace cut 349MB -> ~249MB (suspected ws overflow):
//      * no [N,1024] fused QKV+skip buffer; per-projection GEMMs reuse the
//        raw Wq/Wk/Wv/Wskip tensors as B (no packing)
//      * K/V stored bf16 [N,512]; attn output overwrites Q buffer in place
//  - ws_size guard: if workspace is still too small, write 1e6 sentinel to
//    d_out and return (diagnosable as absmax ~1e6 instead of a crash).
//  - hipMemsetAsync replaced by an explicit zero-fill kernel.
// ============================================================================

#define LN_EPS 1e-5f

static __device__ __forceinline__ float wsum(float v) {
#pragma unroll
  for (int d = 32; d > 0; d >>= 1) v += __shfl_xor(v, d);
  return v;
}
static __device__ __forceinline__ float sigm(float x) { return 1.0f / (1.0f + __expf(-x)); }
static __device__ __forceinline__ unsigned short f2bf(float f) {
  unsigned int u = __float_as_uint(f);
  u += 0x7FFFu + ((u >> 16) & 1u);  // round-to-nearest-even
  return (unsigned short)(u >> 16);
}
static __device__ __forceinline__ float bf2f(unsigned short b) {
  return __uint_as_float(((unsigned int)b) << 16);
}

// ---------------- util ----------------
__global__ __launch_bounds__(256) void k_zero2(int* __restrict__ a, int* __restrict__ b, int n) {
  int i = blockIdx.x * 256 + threadIdx.x;
  if (i < n) { a[i] = 0; b[i] = 0; }
}

__global__ __launch_bounds__(256) void k_sentinel(float* __restrict__ out, int n) {
  int i = blockIdx.x * 256 + threadIdx.x;
  if (i < n) out[i] = 1.0e6f;
}

// ---------------- CSR build (by dst) ----------------
__global__ __launch_bounds__(256) void k_hist(const int* __restrict__ ei, int* __restrict__ cnt, int E) {
  int e = blockIdx.x * 256 + threadIdx.x;
  if (e >= 2 * E) return;
  int d = (e < E) ? ei[E + e] : ei[e - E];
  atomicAdd(&cnt[d], 1);
}

__global__ __launch_bounds__(1024) void k_scan(const int* __restrict__ cnt, int* __restrict__ off, int n) {
  __shared__ int buf[1024];
  __shared__ int carry;
  if (threadIdx.x == 0) carry = 0;
  __syncthreads();
  for (int base = 0; base < n; base += 1024) {
    int i = base + (int)threadIdx.x;
    int v = (i < n) ? cnt[i] : 0;
    buf[threadIdx.x] = v;
    __syncthreads();
    for (int d = 1; d < 1024; d <<= 1) {
      int t = (threadIdx.x >= (unsigned)d) ? buf[threadIdx.x - d] : 0;
      __syncthreads();
      buf[threadIdx.x] += t;
      __syncthreads();
    }
    int c0 = carry;
    if (i < n) off[i] = c0 + buf[threadIdx.x] - v;
    __syncthreads();
    if (threadIdx.x == 0) carry = c0 + buf[1023];
    __syncthreads();
  }
  if (threadIdx.x == 0) off[n] = carry;
}

__global__ __launch_bounds__(256) void k_scatter(const int* __restrict__ ei, const int* __restrict__ off,
                                                 int* __restrict__ cur, int* __restrict__ elist, int E) {
  int e = blockIdx.x * 256 + threadIdx.x;
  if (e >= 2 * E) return;
  int d = (e < E) ? ei[E + e] : ei[e - E];
  int pos = atomicAdd(&cur[d], 1);
  elist[off[d] + pos] = e;
}

// ---------------- pack [Wpn|Wpe] -> B2 [256,128] per iteration ------------
__global__ __launch_bounds__(256) void k_pack2(const float* __restrict__ Wpn, const float* __restrict__ Wpe,
                                               const float* __restrict__ bpn, const float* __restrict__ bpe,
                                               float* __restrict__ B2f, float* __restrict__ bias2) {
  const int S3 = 3 * 256 * 128, S4 = 3 * 128;
  int idx = blockIdx.x * 256 + threadIdx.x;
  if (idx < S3) {
    int i = idx >> 15, r = idx & 32767;
    int k = r >> 7, c = r & 127;
    B2f[idx] = (c < 64) ? Wpn[i * 16384 + k * 64 + c] : Wpe[i * 16384 + k * 64 + (c - 64)];
  } else if (idx < S3 + S4) {
    int j = idx - S3;
    int i = j >> 7, c = j & 127;
    bias2[j] = (c < 64) ? bpn[i * 64 + c] : bpe[i * 64 + c - 64];
  }
}

// ---------------- embeddings ----------------
__global__ __launch_bounds__(256) void k_node_embed(
    const float* __restrict__ x, const int* __restrict__ zk, const float* __restrict__ zt,
    const float* __restrict__ Wn, const float* __restrict__ bn, float* __restrict__ nf, int N) {
  int n = blockIdx.x * 4 + (threadIdx.x >> 6);
  int lane = threadIdx.x & 63;
  if (n >= N) return;
  const float* xr = x + (size_t)n * 6;
  float acc = bn[lane];
#pragma unroll
  for (int d = 0; d < 6; ++d) acc = fmaf(xr[d], Wn[d * 64 + lane], acc);
  int zi = __float2int_rn(xr[2]);
  int idx = 0;
#pragma unroll
  for (int t = 5; t >= 0; --t)
    if (zi == zk[t]) idx = t;
  nf[(size_t)n * 64 + lane] = fmaxf(acc, 0.0f) + zt[idx * 64 + lane];
}

__global__ __launch_bounds__(256) void k_edge_embed(
    const float* __restrict__ x, const float* __restrict__ ea, const int* __restrict__ ei,
    const float* __restrict__ We, const float* __restrict__ be, float* __restrict__ ef, int E) {
  int e = blockIdx.x * 4 + (threadIdx.x >> 6);
  int lane = threadIdx.x & 63;
  if (e >= 2 * E) return;
  int e0 = (e < E) ? e : e - E;
  int s = ei[e];
  int d = (e < E) ? ei[E + e] : ei[e - E];
  const float* ar = ea + (size_t)e0 * 4;
  const float* xs = x + (size_t)s * 6;
  const float* xd = x + (size_t)d * 6;
  float in[7];
  in[0] = ar[0]; in[1] = ar[1]; in[2] = ar[2]; in[3] = ar[3];
  in[4] = xs[0] - xd[0]; in[5] = xs[1] - xd[1]; in[6] = xs[2] - xd[2];
  float acc = be[lane];
#pragma unroll
  for (int dd = 0; dd < 7; ++dd) acc = fmaf(in[dd], We[dd * 64 + lane], acc);
  ef[(size_t)e * 64 + lane] = fmaxf(acc, 0.0f);
}

// ---------------- CBAM ----------------
__global__ __launch_bounds__(256) void k_pool_partial(const float* __restrict__ buf, int n,
                                                      float* __restrict__ pm, float* __restrict__ ps) {
  int col = threadIdx.x & 63, rl = threadIdx.x >> 6;
  float mx = -INFINITY, sm = 0.0f;
  for (int r = blockIdx.x * 4 + rl; r < n; r += gridDim.x * 4) {
    float v = buf[(size_t)r * 64 + col];
    mx = fmaxf(mx, v);
    sm += v;
  }
  __shared__ float smx[256], ssm[256];
  smx[threadIdx.x] = mx;
  ssm[threadIdx.x] = sm;
  __syncthreads();
  if (threadIdx.x < 64) {
    int t = threadIdx.x;
    float m2 = fmaxf(fmaxf(smx[t], smx[t + 64]), fmaxf(smx[t + 128], smx[t + 192]));
    float s2 = ssm[t] + ssm[t + 64] + ssm[t + 128] + ssm[t + 192];
    pm[blockIdx.x * 64 + t] = m2;
    ps[blockIdx.x * 64 + t] = s2;
  }
}

__global__ __launch_bounds__(128) void k_pool_final(
    const float* __restrict__ pm, const float* __restrict__ ps, int n, int nblk,
    const float* __restrict__ w1, const float* __restrict__ b1,
    const float* __restrict__ w2, const float* __restrict__ b2, float* __restrict__ cw) {
  __shared__ float cat[128];
  __shared__ float hid[4];
  int t = threadIdx.x;
  if (t < 64) {
    float mx = -INFINITY, sm = 0.0f;
    for (int p = 0; p < nblk; ++p) {
      mx = fmaxf(mx, pm[p * 64 + t]);
      sm += ps[p * 64 + t];
    }
    cat[t] = mx;
    cat[64 + t] = sm / (float)n;
  }
  __syncthreads();
  if (t < 4) {
    float a = b1[t];
    for (int k = 0; k < 128; ++k) a = fmaf(cat[k], w1[k * 4 + t], a);
    hid[t] = fmaxf(a, 0.0f);
  }
  __syncthreads();
  if (t < 64) {
    float a = b2[t];
#pragma unroll
    for (int h = 0; h < 4; ++h) a = fmaf(hid[h], w2[h * 64 + t], a);
    cw[t] = sigm(a);
  }
}

__global__ __launch_bounds__(256) void k_chan_sp(float* __restrict__ buf, int n,
                                                 const float* __restrict__ cw,
                                                 float* __restrict__ spmax, float* __restrict__ spmean) {
  int r = blockIdx.x * 4 + (threadIdx.x >> 6);
  int lane = threadIdx.x & 63;
  if (r >= n) return;
  float v = buf[(size_t)r * 64 + lane] * cw[lane];
  buf[(size_t)r * 64 + lane] = v;
  float mx = v, sm = v;
#pragma unroll
  for (int d = 32; d > 0; d >>= 1) {
    mx = fmaxf(mx, __shfl_xor(mx, d));
    sm += __shfl_xor(sm, d);
  }
  if (lane == 0) {
    spmax[r] = mx;
    spmean[r] = sm * (1.0f / 64.0f);
  }
}

__global__ __launch_bounds__(256) void k_conv(const float* __restrict__ spmax, const float* __restrict__ spmean,
                                              int n, const float* __restrict__ w1, const float* __restrict__ b1,
                                              const float* __restrict__ w2, const float* __restrict__ b2,
                                              float* __restrict__ s) {
  __shared__ float tl[258];
  int base = blockIdx.x * 256;
  for (int q = threadIdx.x; q < 258; q += 256) {
    int p = base - 1 + q;
    float t = 0.0f;
    if (p >= 0 && p < n) {
      float a = b1[0];
#pragma unroll
      for (int h = 0; h < 5; ++h) {
        int pp = p + h - 2;
        if (pp >= 0 && pp < n) a += spmax[pp] * w1[h] + spmean[pp] * w1[5 + h];
      }
      t = fmaxf(a, 0.0f);
    }
    tl[q] = t;
  }
  __syncthreads();
  int o = base + threadIdx.x;
  if (o < n) {
    float a = b2[0] + tl[threadIdx.x] * w2[0] + tl[threadIdx.x + 1] * w2[1] + tl[threadIdx.x + 2] * w2[2];
    s[o] = sigm(a);
  }
}

__global__ __launch_bounds__(256) void k_row_scale(float* __restrict__ buf, int n, const float* __restrict__ s) {
  int r = blockIdx.x * 4 + (threadIdx.x >> 6);
  int lane = threadIdx.x & 63;
  if (r >= n) return;
  buf[(size_t)r * 64 + lane] *= s[r];
}

// ---------------- agg + concat-LN ----------------
__global__ __launch_bounds__(256) void k_aggcomb(const float* __restrict__ ef, const float* __restrict__ nf,
                                                 const int* __restrict__ off, const int* __restrict__ elist,
                                                 float* __restrict__ comb, const float* __restrict__ g,
                                                 const float* __restrict__ b, int N) {
  int n = blockIdx.x * 4 + (threadIdx.x >> 6);
  int lane = threadIdx.x & 63;
  if (n >= N) return;
  float agg = 0.0f;
  int i0 = off[n], i1 = off[n + 1];
  for (int idx = i0; idx < i1; ++idx) agg += ef[(size_t)elist[idx] * 64 + lane];
  float y0 = nf[(size_t)n * 64 + lane];
  float y1 = agg - y0;
  float s1 = wsum(y0 + y1);
  float s2 = wsum(y0 * y0 + y1 * y1);
  float mu = s1 * (1.0f / 128.0f);
  float var = s2 * (1.0f / 128.0f) - mu * mu;
  float rs = rsqrtf(fmaxf(var, 0.0f) + LN_EPS);
  comb[(size_t)n * 128 + lane] = (y0 - mu) * rs * g[lane] + b[lane];
  comb[(size_t)n * 128 + 64 + lane] = (y1 - mu) * rs * g[64 + lane] + b[64 + lane];
}

// ---------------- tiled GEMM: C[M,NC] = A[M,K] @ B[K,NC] + bias ------------
// BF16OUT=1 stores bf16 (ushort) with ldC element stride; else fp32.
template <int BF16OUT>
__global__ __launch_bounds__(256, 2) void gemm_tile(const float* __restrict__ A, int M, int K,
                                                    const float* __restrict__ B, const float* __restrict__ bias,
                                                    void* __restrict__ Cv, int NC, int ldC) {
  __shared__ __align__(16) float As[64][128];  // [k][m]
  __shared__ __align__(16) float Bs[64][128];  // [k][c] xor-swizzled
  const int tid = threadIdx.x;
  const int bm = blockIdx.x * 128;
  const int bn = blockIdx.y * 128;
  const int tr = (tid >> 4) * 8;
  const int tc = (tid & 15) * 8;
  const int p0 = tc ^ ((tc >> 5) << 2);
  const int p1 = (tc + 4) ^ (((tc + 4) >> 5) << 2);
  float acc[8][8] = {};
  for (int k0 = 0; k0 < K; k0 += 64) {
#pragma unroll
    for (int l = 0; l < 8; ++l) {
      int li = tid + l * 256;
      int r = li >> 4;
      int kq = (li & 15) << 2;
      float4 v = make_float4(0.f, 0.f, 0.f, 0.f);
      if (bm + r < M) v = *(const float4*)(A + (size_t)(bm + r) * K + k0 + kq);
      As[kq + 0][r] = v.x;
      As[kq + 1][r] = v.y;
      As[kq + 2][r] = v.z;
      As[kq + 3][r] = v.w;
    }
#pragma unroll
    for (int l = 0; l < 8; ++l) {
      int li = tid + l * 256;
      int kk = li >> 5;
      int cq = (li & 31) << 2;
      float4 v = *(const float4*)(B + (size_t)(k0 + kk) * NC + bn + cq);
      int p = cq ^ ((cq >> 5) << 2);
      *(float4*)&Bs[kk][p] = v;
    }
    __syncthreads();
#pragma unroll 4
    for (int k = 0; k < 64; ++k) {
      float a[8], bb[8];
      *(float4*)&a[0] = *(const float4*)&As[k][tr];
      *(float4*)&a[4] = *(const float4*)&As[k][tr + 4];
      *(float4*)&bb[0] = *(const float4*)&Bs[k][p0];
      *(float4*)&bb[4] = *(const float4*)&Bs[k][p1];
#pragma unroll
      for (int ii = 0; ii < 8; ++ii)
#pragma unroll
        for (int jj = 0; jj < 8; ++jj) acc[ii][jj] = fmaf(a[ii], bb[jj], acc[ii][jj]);
    }
    __syncthreads();
  }
  float bv[8];
#pragma unroll
  for (int jj = 0; jj < 8; ++jj) bv[jj] = bias[bn + tc + jj];
#pragma unroll
  for (int ii = 0; ii < 8; ++ii) {
    int row = bm + tr + ii;
    if (row >= M) continue;
    if (BF16OUT) {
      unsigned short* Cb = (unsigned short*)Cv;
      union { unsigned short u[8]; uint4 q; } pk;
#pragma unroll
      for (int jj = 0; jj < 8; ++jj) pk.u[jj] = f2bf(acc[ii][jj] + bv[jj]);
      *(uint4*)(Cb + (size_t)row * ldC + bn + tc) = pk.q;
    } else {
      float* Cf = (float*)Cv;
      float4 o0 = make_float4(acc[ii][0] + bv[0], acc[ii][1] + bv[1], acc[ii][2] + bv[2], acc[ii][3] + bv[3]);
      float4 o1 = make_float4(acc[ii][4] + bv[4], acc[ii][5] + bv[5], acc[ii][6] + bv[6], acc[ii][7] + bv[7]);
      *(float4*)(Cf + (size_t)row * ldC + bn + tc) = o0;
      *(float4*)(Cf + (size_t)row * ldC + bn + tc + 4) = o1;
    }
  }
}

// ---------------- attention: per-node wave, online segment softmax + LN ----
// qo: [N,256] fp32 holds Q on entry; overwritten with LN(attn+skip) output.
// kv: [N,512] bf16 (k then v). skipb: [N,256] fp32.
__global__ __launch_bounds__(256) void k_attn(float* __restrict__ qo, const unsigned short* __restrict__ kv,
                                              const float* __restrict__ skipb, const int* __restrict__ off,
                                              const int* __restrict__ elist, const int* __restrict__ ei,
                                              const float* __restrict__ g, const float* __restrict__ b, int N) {
  int n = blockIdx.x * 4 + (threadIdx.x >> 6);
  int lane = threadIdx.x & 63;
  if (n >= N) return;
  float* qb = qo + (size_t)n * 256;
  float q0 = qb[lane], q1 = qb[64 + lane], q2 = qb[128 + lane], q3 = qb[192 + lane];
  float m0 = -INFINITY, m1 = -INFINITY, m2 = -INFINITY, m3 = -INFINITY;
  float l0 = 0.f, l1 = 0.f, l2 = 0.f, l3 = 0.f;
  float a0 = 0.f, a1 = 0.f, a2 = 0.f, a3 = 0.f;
  int i0 = off[n], i1 = off[n + 1];
  for (int idx = i0; idx < i1; ++idx) {
    int eid = elist[idx];
    int s = ei[eid];
    const unsigned short* kb = kv + (size_t)s * 512;
    float d0 = q0 * bf2f(kb[lane]), d1 = q1 * bf2f(kb[64 + lane]),
          d2 = q2 * bf2f(kb[128 + lane]), d3 = q3 * bf2f(kb[192 + lane]);
#pragma unroll
    for (int d = 32; d > 0; d >>= 1) {
      d0 += __shfl_xor(d0, d);
      d1 += __shfl_xor(d1, d);
      d2 += __shfl_xor(d2, d);
      d3 += __shfl_xor(d3, d);
    }
    d0 *= 0.125f; d1 *= 0.125f; d2 *= 0.125f; d3 *= 0.125f;
    float v0 = bf2f(kb[256 + lane]), v1 = bf2f(kb[320 + lane]),
          v2 = bf2f(kb[384 + lane]), v3 = bf2f(kb[448 + lane]);
    float nm, sc, p;
    nm = fmaxf(m0, d0); sc = __expf(m0 - nm); p = __expf(d0 - nm);
    l0 = l0 * sc + p; a0 = fmaf(p, v0, a0 * sc); m0 = nm;
    nm = fmaxf(m1, d1); sc = __expf(m1 - nm); p = __expf(d1 - nm);
    l1 = l1 * sc + p; a1 = fmaf(p, v1, a1 * sc); m1 = nm;
    nm = fmaxf(m2, d2); sc = __expf(m2 - nm); p = __expf(d2 - nm);
    l2 = l2 * sc + p; a2 = fmaf(p, v2, a2 * sc); m2 = nm;
    nm = fmaxf(m3, d3); sc = __expf(m3 - nm); p = __expf(d3 - nm);
    l3 = l3 * sc + p; a3 = fmaf(p, v3, a3 * sc); m3 = nm;
  }
  const float* sb = skipb + (size_t)n * 256;
  float v0 = sb[lane] + ((l0 > 0.f) ? a0 / l0 : 0.f);
  float v1 = sb[64 + lane] + ((l1 > 0.f) ? a1 / l1 : 0.f);
  float v2 = sb[128 + lane] + ((l2 > 0.f) ? a2 / l2 : 0.f);
  float v3 = sb[192 + lane] + ((l3 > 0.f) ? a3 / l3 : 0.f);
  float s1 = wsum(v0 + v1 + v2 + v3);
  float s2 = wsum(v0 * v0 + v1 * v1 + v2 * v2 + v3 * v3);
  float mu = s1 * (1.0f / 256.0f);
  float var = s2 * (1.0f / 256.0f) - mu * mu;
  float rs = rsqrtf(fmaxf(var, 0.0f) + LN_EPS);
  qb[lane] = (v0 - mu) * rs * g[lane] + b[lane];
  qb[64 + lane] = (v1 - mu) * rs * g[64 + lane] + b[64 + lane];
  qb[128 + lane] = (v2 - mu) * rs * g[128 + lane] + b[128 + lane];
  qb[192 + lane] = (v3 - mu) * rs * g[192 + lane] + b[192 + lane];
}

// ---------------- gated residual updates ----------------
__global__ __launch_bounds__(256) void k_gate_node(float* __restrict__ nf, const float* __restrict__ proj,
                                                   const float* __restrict__ Wg, const float* __restrict__ bg,
                                                   int N) {
  __shared__ float W[128 * 64];
  for (int t = threadIdx.x; t < 128 * 64; t += 256) W[t] = Wg[t];
  __syncthreads();
  const int lane = threadIdx.x & 63;
  const int w = threadIdx.x >> 6;
  const float bb = bg[lane];
  for (int n = blockIdx.x * 4 + w; n < N; n += gridDim.x * 4) {
    float vA = nf[(size_t)n * 64 + lane];
    float vB = proj[(size_t)n * 128 + lane];
    float acc = bb;
#pragma unroll
    for (int k = 0; k < 64; ++k) acc = fmaf(__shfl(vA, k), W[k * 64 + lane], acc);
#pragma unroll
    for (int k = 0; k < 64; ++k) acc = fmaf(__shfl(vB, k), W[(64 + k) * 64 + lane], acc);
    float gg = sigm(acc);
    nf[(size_t)n * 64 + lane] = vA * gg + vB * (1.0f - gg);
  }
}

__global__ __launch_bounds__(256) void k_gate_edge(float* __restrict__ ef, const float* __restrict__ proj,
                                                   const int* __restrict__ ei, const float* __restrict__ Wg,
                                                   const float* __restrict__ bg, int E) {
  __shared__ float W[128 * 64];
  for (int t = threadIdx.x; t < 128 * 64; t += 256) W[t] = Wg[t];
  __syncthreads();
  const int lane = threadIdx.x & 63;
  const int w = threadIdx.x >> 6;
  const float bb = bg[lane];
  const int E2 = 2 * E;
  for (int e = blockIdx.x * 4 + w; e < E2; e += gridDim.x * 4) {
    float vA = ef[(size_t)e * 64 + lane];
    int s = ei[e];
    float vB = proj[(size_t)s * 128 + 64 + lane];
    float acc = bb;
#pragma unroll
    for (int k = 0; k < 64; ++k) acc = fmaf(__shfl(vA, k), W[k * 64 + lane], acc);
#pragma unroll
    for (int k = 0; k < 64; ++k) acc = fmaf(__shfl(vB, k), W[(64 + k) * 64 + lane], acc);
    float gg = sigm(acc);
    ef[(size_t)e * 64 + lane] = vA * gg + vB * (1.0f - gg);
  }
}

// ---------------- classifier ----------------
__global__ __launch_bounds__(256) void k_clf(const float* __restrict__ nf, const int* __restrict__ ei,
                                             const float* __restrict__ Wc1, const float* __restrict__ bc1,
                                             const float* __restrict__ Wc2, const float* __restrict__ bc2,
                                             float* __restrict__ out, int E) {
  __shared__ float W[128 * 64];
  for (int t = threadIdx.x; t < 128 * 64; t += 256) W[t] = Wc1[t];
  __syncthreads();
  const int lane = threadIdx.x & 63;
  const int w = threadIdx.x >> 6;
  const float b1 = bc1[lane];
  const float w2 = Wc2[lane];
  const float b2 = bc2[0];
  for (int e = blockIdx.x * 4 + w; e < E; e += gridDim.x * 4) {
    int s = ei[e], t = ei[E + e];
    float vA = nf[(size_t)s * 64 + lane];
    float vB = nf[(size_t)t * 64 + lane];
    float acc = b1;
#pragma unroll
    for (int k = 0; k < 64; ++k) acc = fmaf(__shfl(vA, k), W[k * 64 + lane], acc);
#pragma unroll
    for (int k = 0; k < 64; ++k) acc = fmaf(__shfl(vB, k), W[(64 + k) * 64 + lane], acc);
    float r = fmaxf(acc, 0.0f) * w2;
    r = wsum(r);
    if (lane == 0) out[e] = r + b2;
  }
}

// ============================================================================
extern "C" void kernel_launch(void* const* d_in, const int* in_sizes, int n_in,
                              void* d_out, int out_size, void* d_ws, size_t ws_size,
                              hipStream_t stream) {
  const float* x = (const float*)d_in[0];
  const float* edge_attr = (const float*)d_in[1];
  const int* ei = (const int*)d_in[2];
  const int* zk = (const int*)d_in[3];
  const float* z_table = (const float*)d_in[4];
  const float* W_node = (const float*)d_in[5];
  const float* b_node = (const float*)d_in[6];
  const float* W_edge = (const float*)d_in[7];
  const float* b_edge = (const float*)d_in[8];
  const float* cn_w1 = (const float*)d_in[9];
  const float* cn_b1 = (const float*)d_in[10];
  const float* cn_w2 = (const float*)d_in[11];
  const float* cn_b2 = (const float*)d_in[12];
  const float* cn_cw1 = (const float*)d_in[13];
  const float* cn_cb1 = (const float*)d_in[14];
  const float* cn_cw2 = (const float*)d_in[15];
  const float* cn_cb2 = (const float*)d_in[16];
  const float* ce_w1 = (const float*)d_in[17];
  const float* ce_b1 = (const float*)d_in[18];
  const float* ce_w2 = (const float*)d_in[19];
  const float* ce_b2 = (const float*)d_in[20];
  const float* ce_cw1 = (const float*)d_in[21];
  const float* ce_cb1 = (const float*)d_in[22];
  const float* ce_cw2 = (const float*)d_in[23];
  const float* ce_cb2 = (const float*)d_in[24];
  const float* ln_comb_g = (const float*)d_in[25];
  const float* ln_comb_b = (const float*)d_in[26];
  const float* Wq = (const float*)d_in[27];
  const float* bq = (const float*)d_in[28];
  const float* Wk = (const float*)d_in[29];
  const float* bk = (const float*)d_in[30];
  const float* Wv = (const float*)d_in[31];
  const float* bv = (const float*)d_in[32];
  const float* Wskip = (const float*)d_in[33];
  const float* bskip = (const float*)d_in[34];
  const float* ln_tc_g = (const float*)d_in[35];
  const float* ln_tc_b = (const float*)d_in[36];
  const float* Wpn = (const float*)d_in[37];
  const float* bpn = (const float*)d_in[38];
  const float* Wpe = (const float*)d_in[39];
  const float* bpe = (const float*)d_in[40];
  const float* Wg = (const float*)d_in[41];
  const float* bg = (const float*)d_in[42];
  const float* Wc1 = (const float*)d_in[43];
  const float* bc1 = (const float*)d_in[44];
  const float* Wc2 = (const float*)d_in[45];
  const float* bc2 = (const float*)d_in[46];
  float* out = (float*)d_out;

  const int N = in_sizes[0] / 6;   // 50000
  const int E = in_sizes[2] / 2;   // 100000
  const int E2 = 2 * E;

  // ---- workspace carve (~249 MB peak) ----
  char* p = (char*)d_ws;
  auto carve = [&](size_t bytes) -> void* {
    void* r = (void*)p;
    p += (bytes + 255) & ~(size_t)255;
    return r;
  };
  float* qo = (float*)carve((size_t)N * 256 * 4);           // Q, then attn output
  float* skipb = (float*)carve((size_t)N * 256 * 4);        // skip projection
  unsigned short* kvb = (unsigned short*)carve((size_t)N * 512 * 2);  // bf16 K|V
  float* ef = (float*)carve((size_t)E2 * 64 * 4);
  float* nf = (float*)carve((size_t)N * 64 * 4);
  float* comb = (float*)carve((size_t)N * 128 * 4);         // comb, then [npj|pe]
  float* B2f = (float*)carve((size_t)3 * 256 * 128 * 4);
  float* bias2 = (float*)carve((size_t)3 * 128 * 4);
  int* cnt = (int*)carve((size_t)N * 4);
  int* cur = (int*)carve((size_t)N * 4);
  int* off = (int*)carve((size_t)(N + 1) * 4);
  int* elist = (int*)carve((size_t)E2 * 4);
  float* pm = (float*)carve((size_t)120 * 64 * 4);
  float* ps = (float*)carve((size_t)120 * 64 * 4);
  float* cwv = (float*)carve(64 * 4);
  float* spmax = (float*)carve((size_t)E2 * 4);
  float* spmean = (float*)carve((size_t)E2 * 4);
  float* sconv = (float*)carve((size_t)E2 * 4);
  size_t need = (size_t)(p - (char*)d_ws);

  auto cdiv = [](int a, int b) { return (a + b - 1) / b; };

  if (ws_size < need) {
    // Diagnostic path: workspace too small -> unmistakable sentinel output.
    k_sentinel<<<cdiv(E, 256), 256, 0, stream>>>(out, E);
    return;
  }

  // ---- CSR by dst ----
  k_zero2<<<cdiv(N, 256), 256, 0, stream>>>(cnt, cur, N);
  k_hist<<<cdiv(E2, 256), 256, 0, stream>>>(ei, cnt, E);
  k_scan<<<1, 1024, 0, stream>>>(cnt, off, N);
  k_scatter<<<cdiv(E2, 256), 256, 0, stream>>>(ei, off, cur, elist, E);

  // ---- pack [Wpn|Wpe] ----
  const int PACK = 3 * 256 * 128 + 3 * 128;
  k_pack2<<<cdiv(PACK, 256), 256, 0, stream>>>(Wpn, Wpe, bpn, bpe, B2f, bias2);

  // ---- embeddings ----
  k_node_embed<<<cdiv(N, 4), 256, 0, stream>>>(x, zk, z_table, W_node, b_node, nf, N);
  k_edge_embed<<<cdiv(E2, 4), 256, 0, stream>>>(x, edge_attr, ei, W_edge, b_edge, ef, E);

  // ---- CBAM on nodes then edges ----
  auto run_cbam = [&](float* buf, int rows, const float* w1, const float* b1, const float* w2,
                      const float* b2, const float* cw1, const float* cb1, const float* cw2,
                      const float* cb2) {
    k_pool_partial<<<120, 256, 0, stream>>>(buf, rows, pm, ps);
    k_pool_final<<<1, 128, 0, stream>>>(pm, ps, rows, 120, w1, b1, w2, b2, cwv);
    k_chan_sp<<<cdiv(rows, 4), 256, 0, stream>>>(buf, rows, cwv, spmax, spmean);
    k_conv<<<cdiv(rows, 256), 256, 0, stream>>>(spmax, spmean, rows, cw1, cb1, cw2, cb2, sconv);
    k_row_scale<<<cdiv(rows, 4), 256, 0, stream>>>(buf, rows, sconv);
  };
  run_cbam(nf, N, cn_w1, cn_b1, cn_w2, cn_b2, cn_cw1, cn_cb1, cn_cw2, cn_cb2);
  run_cbam(ef, E2, ce_w1, ce_b1, ce_w2, ce_b2, ce_cw1, ce_cb1, ce_cw2, ce_cb2);

  // ---- T = 3 message-passing iterations ----
  dim3 gq(cdiv(N, 128), 2);   // NC=256
  dim3 gp(cdiv(N, 128), 1);   // NC=128
  for (int i = 0; i < 3; ++i) {
    const size_t wof = (size_t)i * 128 * 256;
    const size_t bof = (size_t)i * 256;
    k_aggcomb<<<cdiv(N, 4), 256, 0, stream>>>(ef, nf, off, elist, comb,
                                              ln_comb_g + (size_t)i * 128, ln_comb_b + (size_t)i * 128, N);
    // Q (fp32), K (bf16), V (bf16), skip (fp32) projections
    gemm_tile<0><<<gq, 256, 0, stream>>>(comb, N, 128, Wq + wof, bq + bof, qo, 256, 256);
    gemm_tile<1><<<gq, 256, 0, stream>>>(comb, N, 128, Wk + wof, bk + bof, kvb, 256, 512);
    gemm_tile<1><<<gq, 256, 0, stream>>>(comb, N, 128, Wv + wof, bv + bof, kvb + 256, 256, 512);
    gemm_tile<0><<<gq, 256, 0, stream>>>(comb, N, 128, Wskip + wof, bskip + bof, skipb, 256, 256);
    k_attn<<<cdiv(N, 4), 256, 0, stream>>>(qo, kvb, skipb, off, elist, ei,
                                           ln_tc_g + (size_t)i * 256, ln_tc_b + (size_t)i * 256, N);
    // [npj | pe] projection
    gemm_tile<0><<<gp, 256, 0, stream>>>(qo, N, 256, B2f + (size_t)i * 256 * 128,
                                         bias2 + (size_t)i * 128, comb, 128, 128);
    k_gate_node<<<512, 256, 0, stream>>>(nf, comb, Wg + (size_t)i * 128 * 64, bg + (size_t)i * 64, N);
    k_gate_edge<<<512, 256, 0, stream>>>(ef, comb, ei, Wg + (size_t)i * 128 * 64, bg + (size_t)i * 64, E);
  }

  // ---- classifier ----
  k_clf<<<512, 256, 0, stream>>>(nf, ei, Wc1, bc1, Wc2, bc2, out, E);
  (void)out_size;
  (void)n_in;
}

// Round 3
// 2308.863 us; speedup vs baseline: 1.2387x; 1.2387x over previous
//
#include <hip/hip_runtime.h>

// ============================================================================
// New_LinkNet GNN forward — fp32 with bf16 K/V staging.
// Round-3 changes vs round 2 (2860us, gate/clf wave-GEMV = LDS-pipe bound on
// 25.6M ds_bpermute):
//  - k_gate_node / k_gate_edge / k_clf (shfl-broadcast GEMV) replaced by:
//      * extended proj GEMM B2ext = [Wpn|Wpe|Wpn@Wg2|Wpe@Wg2] -> per-node
//        [npj|pe|vn|ve] (vn/ve are the proj-side gate-logit halves)
//      * gemm64: [M,64]@[64,64] tiled GEMM for ef@Wg1, nf@Wg1, nf@Wc1-halves
//      * streaming elementwise update kernels with coalesced row gathers
//  - buffers aliased (P=skipb, Se=qo, Sn=kvb, AB=qo); peak ws ~249MB as before
// ============================================================================

#define LN_EPS 1e-5f

static __device__ __forceinline__ float wsum(float v) {
#pragma unroll
  for (int d = 32; d > 0; d >>= 1) v += __shfl_xor(v, d);
  return v;
}
static __device__ __forceinline__ float sigm(float x) { return 1.0f / (1.0f + __expf(-x)); }
static __device__ __forceinline__ unsigned short f2bf(float f) {
  unsigned int u = __float_as_uint(f);
  u += 0x7FFFu + ((u >> 16) & 1u);  // round-to-nearest-even
  return (unsigned short)(u >> 16);
}
static __device__ __forceinline__ float bf2f(unsigned short b) {
  return __uint_as_float(((unsigned int)b) << 16);
}

// ---------------- util ----------------
__global__ __launch_bounds__(256) void k_zero2(int* __restrict__ a, int* __restrict__ b, int n) {
  int i = blockIdx.x * 256 + threadIdx.x;
  if (i < n) { a[i] = 0; b[i] = 0; }
}

__global__ __launch_bounds__(256) void k_sentinel(float* __restrict__ out, int n) {
  int i = blockIdx.x * 256 + threadIdx.x;
  if (i < n) out[i] = 1.0e6f;
}

// ---------------- CSR build (by dst) ----------------
__global__ __launch_bounds__(256) void k_hist(const int* __restrict__ ei, int* __restrict__ cnt, int E) {
  int e = blockIdx.x * 256 + threadIdx.x;
  if (e >= 2 * E) return;
  int d = (e < E) ? ei[E + e] : ei[e - E];
  atomicAdd(&cnt[d], 1);
}

__global__ __launch_bounds__(1024) void k_scan(const int* __restrict__ cnt, int* __restrict__ off, int n) {
  __shared__ int buf[1024];
  __shared__ int carry;
  if (threadIdx.x == 0) carry = 0;
  __syncthreads();
  for (int base = 0; base < n; base += 1024) {
    int i = base + (int)threadIdx.x;
    int v = (i < n) ? cnt[i] : 0;
    buf[threadIdx.x] = v;
    __syncthreads();
    for (int d = 1; d < 1024; d <<= 1) {
      int t = (threadIdx.x >= (unsigned)d) ? buf[threadIdx.x - d] : 0;
      __syncthreads();
      buf[threadIdx.x] += t;
      __syncthreads();
    }
    int c0 = carry;
    if (i < n) off[i] = c0 + buf[threadIdx.x] - v;
    __syncthreads();
    if (threadIdx.x == 0) carry = c0 + buf[1023];
    __syncthreads();
  }
  if (threadIdx.x == 0) off[n] = carry;
}

__global__ __launch_bounds__(256) void k_scatter(const int* __restrict__ ei, const int* __restrict__ off,
                                                 int* __restrict__ cur, int* __restrict__ elist, int E) {
  int e = blockIdx.x * 256 + threadIdx.x;
  if (e >= 2 * E) return;
  int d = (e < E) ? ei[E + e] : ei[e - E];
  int pos = atomicAdd(&cur[d], 1);
  elist[off[d] + pos] = e;
}

// ------ pack B2ext [256, 256] = [Wpn | Wpe | Wpn@Wg2 | Wpe@Wg2] per iter ---
__global__ __launch_bounds__(256) void k_pack2(const float* __restrict__ Wpn, const float* __restrict__ Wpe,
                                               const float* __restrict__ bpn, const float* __restrict__ bpe,
                                               const float* __restrict__ Wg,
                                               float* __restrict__ B2f, float* __restrict__ bias2) {
  const int S3 = 3 * 256 * 256, S4 = 3 * 256;
  int idx = blockIdx.x * 256 + threadIdx.x;
  if (idx < S3) {
    int i = idx >> 16, r = idx & 65535;
    int k = r >> 8, c = r & 255;
    float v;
    if (c < 64) v = Wpn[i * 16384 + k * 64 + c];
    else if (c < 128) v = Wpe[i * 16384 + k * 64 + (c - 64)];
    else {
      const float* Wsrc = (c < 192) ? Wpn : Wpe;
      int cc = c & 63;
      float acc = 0.f;
      for (int j = 0; j < 64; ++j)
        acc = fmaf(Wsrc[i * 16384 + k * 64 + j], Wg[i * 8192 + (64 + j) * 64 + cc], acc);
      v = acc;
    }
    B2f[idx] = v;
  } else if (idx < S3 + S4) {
    int j = idx - S3;
    int i = j >> 8, c = j & 255;
    float v;
    if (c < 64) v = bpn[i * 64 + c];
    else if (c < 128) v = bpe[i * 64 + c - 64];
    else {
      const float* bsrc = (c < 192) ? bpn : bpe;
      int cc = c & 63;
      float acc = 0.f;
      for (int jj = 0; jj < 64; ++jj)
        acc = fmaf(bsrc[i * 64 + jj], Wg[i * 8192 + (64 + jj) * 64 + cc], acc);
      v = acc;
    }
    bias2[j] = v;
  }
}

// ---------------- embeddings ----------------
__global__ __launch_bounds__(256) void k_node_embed(
    const float* __restrict__ x, const int* __restrict__ zk, const float* __restrict__ zt,
    const float* __restrict__ Wn, const float* __restrict__ bn, float* __restrict__ nf, int N) {
  int n = blockIdx.x * 4 + (threadIdx.x >> 6);
  int lane = threadIdx.x & 63;
  if (n >= N) return;
  const float* xr = x + (size_t)n * 6;
  float acc = bn[lane];
#pragma unroll
  for (int d = 0; d < 6; ++d) acc = fmaf(xr[d], Wn[d * 64 + lane], acc);
  int zi = __float2int_rn(xr[2]);
  int idx = 0;
#pragma unroll
  for (int t = 5; t >= 0; --t)
    if (zi == zk[t]) idx = t;
  nf[(size_t)n * 64 + lane] = fmaxf(acc, 0.0f) + zt[idx * 64 + lane];
}

__global__ __launch_bounds__(256) void k_edge_embed(
    const float* __restrict__ x, const float* __restrict__ ea, const int* __restrict__ ei,
    const float* __restrict__ We, const float* __restrict__ be, float* __restrict__ ef, int E) {
  int e = blockIdx.x * 4 + (threadIdx.x >> 6);
  int lane = threadIdx.x & 63;
  if (e >= 2 * E) return;
  int e0 = (e < E) ? e : e - E;
  int s = ei[e];
  int d = (e < E) ? ei[E + e] : ei[e - E];
  const float* ar = ea + (size_t)e0 * 4;
  const float* xs = x + (size_t)s * 6;
  const float* xd = x + (size_t)d * 6;
  float in[7];
  in[0] = ar[0]; in[1] = ar[1]; in[2] = ar[2]; in[3] = ar[3];
  in[4] = xs[0] - xd[0]; in[5] = xs[1] - xd[1]; in[6] = xs[2] - xd[2];
  float acc = be[lane];
#pragma unroll
  for (int dd = 0; dd < 7; ++dd) acc = fmaf(in[dd], We[dd * 64 + lane], acc);
  ef[(size_t)e * 64 + lane] = fmaxf(acc, 0.0f);
}

// ---------------- CBAM ----------------
__global__ __launch_bounds__(256) void k_pool_partial(const float* __restrict__ buf, int n,
                                                      float* __restrict__ pm, float* __restrict__ ps) {
  int col = threadIdx.x & 63, rl = threadIdx.x >> 6;
  float mx = -INFINITY, sm = 0.0f;
  for (int r = blockIdx.x * 4 + rl; r < n; r += gridDim.x * 4) {
    float v = buf[(size_t)r * 64 + col];
    mx = fmaxf(mx, v);
    sm += v;
  }
  __shared__ float smx[256], ssm[256];
  smx[threadIdx.x] = mx;
  ssm[threadIdx.x] = sm;
  __syncthreads();
  if (threadIdx.x < 64) {
    int t = threadIdx.x;
    float m2 = fmaxf(fmaxf(smx[t], smx[t + 64]), fmaxf(smx[t + 128], smx[t + 192]));
    float s2 = ssm[t] + ssm[t + 64] + ssm[t + 128] + ssm[t + 192];
    pm[blockIdx.x * 64 + t] = m2;
    ps[blockIdx.x * 64 + t] = s2;
  }
}

__global__ __launch_bounds__(128) void k_pool_final(
    const float* __restrict__ pm, const float* __restrict__ ps, int n, int nblk,
    const float* __restrict__ w1, const float* __restrict__ b1,
    const float* __restrict__ w2, const float* __restrict__ b2, float* __restrict__ cw) {
  __shared__ float cat[128];
  __shared__ float hid[4];
  int t = threadIdx.x;
  if (t < 64) {
    float mx = -INFINITY, sm = 0.0f;
    for (int p = 0; p < nblk; ++p) {
      mx = fmaxf(mx, pm[p * 64 + t]);
      sm += ps[p * 64 + t];
    }
    cat[t] = mx;
    cat[64 + t] = sm / (float)n;
  }
  __syncthreads();
  if (t < 4) {
    float a = b1[t];
    for (int k = 0; k < 128; ++k) a = fmaf(cat[k], w1[k * 4 + t], a);
    hid[t] = fmaxf(a, 0.0f);
  }
  __syncthreads();
  if (t < 64) {
    float a = b2[t];
#pragma unroll
    for (int h = 0; h < 4; ++h) a = fmaf(hid[h], w2[h * 64 + t], a);
    cw[t] = sigm(a);
  }
}

__global__ __launch_bounds__(256) void k_chan_sp(float* __restrict__ buf, int n,
                                                 const float* __restrict__ cw,
                                                 float* __restrict__ spmax, float* __restrict__ spmean) {
  int r = blockIdx.x * 4 + (threadIdx.x >> 6);
  int lane = threadIdx.x & 63;
  if (r >= n) return;
  float v = buf[(size_t)r * 64 + lane] * cw[lane];
  buf[(size_t)r * 64 + lane] = v;
  float mx = v, sm = v;
#pragma unroll
  for (int d = 32; d > 0; d >>= 1) {
    mx = fmaxf(mx, __shfl_xor(mx, d));
    sm += __shfl_xor(sm, d);
  }
  if (lane == 0) {
    spmax[r] = mx;
    spmean[r] = sm * (1.0f / 64.0f);
  }
}

__global__ __launch_bounds__(256) void k_conv(const float* __restrict__ spmax, const float* __restrict__ spmean,
                                              int n, const float* __restrict__ w1, const float* __restrict__ b1,
                                              const float* __restrict__ w2, const float* __restrict__ b2,
                                              float* __restrict__ s) {
  __shared__ float tl[258];
  int base = blockIdx.x * 256;
  for (int q = threadIdx.x; q < 258; q += 256) {
    int p = base - 1 + q;
    float t = 0.0f;
    if (p >= 0 && p < n) {
      float a = b1[0];
#pragma unroll
      for (int h = 0; h < 5; ++h) {
        int pp = p + h - 2;
        if (pp >= 0 && pp < n) a += spmax[pp] * w1[h] + spmean[pp] * w1[5 + h];
      }
      t = fmaxf(a, 0.0f);
    }
    tl[q] = t;
  }
  __syncthreads();
  int o = base + threadIdx.x;
  if (o < n) {
    float a = b2[0] + tl[threadIdx.x] * w2[0] + tl[threadIdx.x + 1] * w2[1] + tl[threadIdx.x + 2] * w2[2];
    s[o] = sigm(a);
  }
}

__global__ __launch_bounds__(256) void k_row_scale(float* __restrict__ buf, int n, const float* __restrict__ s) {
  int r = blockIdx.x * 4 + (threadIdx.x >> 6);
  int lane = threadIdx.x & 63;
  if (r >= n) return;
  buf[(size_t)r * 64 + lane] *= s[r];
}

// ---------------- agg + concat-LN ----------------
__global__ __launch_bounds__(256) void k_aggcomb(const float* __restrict__ ef, const float* __restrict__ nf,
                                                 const int* __restrict__ off, const int* __restrict__ elist,
                                                 float* __restrict__ comb, const float* __restrict__ g,
                                                 const float* __restrict__ b, int N) {
  int n = blockIdx.x * 4 + (threadIdx.x >> 6);
  int lane = threadIdx.x & 63;
  if (n >= N) return;
  float agg = 0.0f;
  int i0 = off[n], i1 = off[n + 1];
  for (int idx = i0; idx < i1; ++idx) agg += ef[(size_t)elist[idx] * 64 + lane];
  float y0 = nf[(size_t)n * 64 + lane];
  float y1 = agg - y0;
  float s1 = wsum(y0 + y1);
  float s2 = wsum(y0 * y0 + y1 * y1);
  float mu = s1 * (1.0f / 128.0f);
  float var = s2 * (1.0f / 128.0f) - mu * mu;
  float rs = rsqrtf(fmaxf(var, 0.0f) + LN_EPS);
  comb[(size_t)n * 128 + lane] = (y0 - mu) * rs * g[lane] + b[lane];
  comb[(size_t)n * 128 + 64 + lane] = (y1 - mu) * rs * g[64 + lane] + b[64 + lane];
}

// ---------------- tiled GEMM: C[M,NC] = A[M,K] @ B[K,NC] + bias ------------
template <int BF16OUT>
__global__ __launch_bounds__(256, 2) void gemm_tile(const float* __restrict__ A, int M, int K,
                                                    const float* __restrict__ B, const float* __restrict__ bias,
                                                    void* __restrict__ Cv, int NC, int ldC) {
  __shared__ __align__(16) float As[64][128];  // [k][m]
  __shared__ __align__(16) float Bs[64][128];  // [k][c] xor-swizzled
  const int tid = threadIdx.x;
  const int bm = blockIdx.x * 128;
  const int bn = blockIdx.y * 128;
  const int tr = (tid >> 4) * 8;
  const int tc = (tid & 15) * 8;
  const int p0 = tc ^ ((tc >> 5) << 2);
  const int p1 = (tc + 4) ^ (((tc + 4) >> 5) << 2);
  float acc[8][8] = {};
  for (int k0 = 0; k0 < K; k0 += 64) {
#pragma unroll
    for (int l = 0; l < 8; ++l) {
      int li = tid + l * 256;
      int r = li >> 4;
      int kq = (li & 15) << 2;
      float4 v = make_float4(0.f, 0.f, 0.f, 0.f);
      if (bm + r < M) v = *(const float4*)(A + (size_t)(bm + r) * K + k0 + kq);
      As[kq + 0][r] = v.x;
      As[kq + 1][r] = v.y;
      As[kq + 2][r] = v.z;
      As[kq + 3][r] = v.w;
    }
#pragma unroll
    for (int l = 0; l < 8; ++l) {
      int li = tid + l * 256;
      int kk = li >> 5;
      int cq = (li & 31) << 2;
      float4 v = *(const float4*)(B + (size_t)(k0 + kk) * NC + bn + cq);
      int p = cq ^ ((cq >> 5) << 2);
      *(float4*)&Bs[kk][p] = v;
    }
    __syncthreads();
#pragma unroll 4
    for (int k = 0; k < 64; ++k) {
      float a[8], bb[8];
      *(float4*)&a[0] = *(const float4*)&As[k][tr];
      *(float4*)&a[4] = *(const float4*)&As[k][tr + 4];
      *(float4*)&bb[0] = *(const float4*)&Bs[k][p0];
      *(float4*)&bb[4] = *(const float4*)&Bs[k][p1];
#pragma unroll
      for (int ii = 0; ii < 8; ++ii)
#pragma unroll
        for (int jj = 0; jj < 8; ++jj) acc[ii][jj] = fmaf(a[ii], bb[jj], acc[ii][jj]);
    }
    __syncthreads();
  }
  float bv[8];
#pragma unroll
  for (int jj = 0; jj < 8; ++jj) bv[jj] = bias[bn + tc + jj];
#pragma unroll
  for (int ii = 0; ii < 8; ++ii) {
    int row = bm + tr + ii;
    if (row >= M) continue;
    if (BF16OUT) {
      unsigned short* Cb = (unsigned short*)Cv;
      union { unsigned short u[8]; uint4 q; } pk;
#pragma unroll
      for (int jj = 0; jj < 8; ++jj) pk.u[jj] = f2bf(acc[ii][jj] + bv[jj]);
      *(uint4*)(Cb + (size_t)row * ldC + bn + tc) = pk.q;
    } else {
      float* Cf = (float*)Cv;
      float4 o0 = make_float4(acc[ii][0] + bv[0], acc[ii][1] + bv[1], acc[ii][2] + bv[2], acc[ii][3] + bv[3]);
      float4 o1 = make_float4(acc[ii][4] + bv[4], acc[ii][5] + bv[5], acc[ii][6] + bv[6], acc[ii][7] + bv[7]);
      *(float4*)(Cf + (size_t)row * ldC + bn + tc) = o0;
      *(float4*)(Cf + (size_t)row * ldC + bn + tc + 4) = o1;
    }
  }
}

// ---------------- small GEMM: C[M,64] = A[M,64] @ W[64,64] (no bias) -------
__global__ __launch_bounds__(256) void gemm64(const float* __restrict__ A, int M,
                                              const float* __restrict__ W, float* __restrict__ C) {
  __shared__ __align__(16) float As[64][68];
  __shared__ __align__(16) float Ws[64][68];
  const int tid = threadIdx.x;
  const int row0 = blockIdx.x * 64;
  const int rr = tid >> 4;
  const int c4 = (tid & 15) << 2;
#pragma unroll
  for (int l = 0; l < 4; ++l) {
    int k = rr + l * 16;
    *(float4*)&Ws[k][c4] = *(const float4*)(W + k * 64 + c4);
    float4 v = make_float4(0.f, 0.f, 0.f, 0.f);
    if (row0 + k < M) v = *(const float4*)(A + (size_t)(row0 + k) * 64 + c4);
    *(float4*)&As[k][c4] = v;
  }
  __syncthreads();
  const int tr = (tid >> 4) * 4;
  const int tc = (tid & 15) * 4;
  float acc[4][4] = {};
#pragma unroll
  for (int k = 0; k < 64; k += 4) {
    float4 wv[4];
#pragma unroll
    for (int j = 0; j < 4; ++j) wv[j] = *(const float4*)&Ws[k + j][tc];
#pragma unroll
    for (int i = 0; i < 4; ++i) {
      float4 av = *(const float4*)&As[tr + i][k];
      const float aa[4] = {av.x, av.y, av.z, av.w};
#pragma unroll
      for (int j = 0; j < 4; ++j) {
        const float* wj = (const float*)&wv[j];
#pragma unroll
        for (int c = 0; c < 4; ++c) acc[i][c] = fmaf(aa[j], wj[c], acc[i][c]);
      }
    }
  }
#pragma unroll
  for (int i = 0; i < 4; ++i) {
    int row = row0 + tr + i;
    if (row < M)
      *(float4*)(C + (size_t)row * 64 + tc) = make_float4(acc[i][0], acc[i][1], acc[i][2], acc[i][3]);
  }
}

// ---------------- attention: per-node wave, online segment softmax + LN ----
__global__ __launch_bounds__(256) void k_attn(float* __restrict__ qo, const unsigned short* __restrict__ kv,
                                              const float* __restrict__ skipb, const int* __restrict__ off,
                                              const int* __restrict__ elist, const int* __restrict__ ei,
                                              const float* __restrict__ g, const float* __restrict__ b, int N) {
  int n = blockIdx.x * 4 + (threadIdx.x >> 6);
  int lane = threadIdx.x & 63;
  if (n >= N) return;
  float* qb = qo + (size_t)n * 256;
  float q0 = qb[lane], q1 = qb[64 + lane], q2 = qb[128 + lane], q3 = qb[192 + lane];
  float m0 = -INFINITY, m1 = -INFINITY, m2 = -INFINITY, m3 = -INFINITY;
  float l0 = 0.f, l1 = 0.f, l2 = 0.f, l3 = 0.f;
  float a0 = 0.f, a1 = 0.f, a2 = 0.f, a3 = 0.f;
  int i0 = off[n], i1 = off[n + 1];
  for (int idx = i0; idx < i1; ++idx) {
    int eid = elist[idx];
    int s = ei[eid];
    const unsigned short* kb = kv + (size_t)s * 512;
    float d0 = q0 * bf2f(kb[lane]), d1 = q1 * bf2f(kb[64 + lane]),
          d2 = q2 * bf2f(kb[128 + lane]), d3 = q3 * bf2f(kb[192 + lane]);
#pragma unroll
    for (int d = 32; d > 0; d >>= 1) {
      d0 += __shfl_xor(d0, d);
      d1 += __shfl_xor(d1, d);
      d2 += __shfl_xor(d2, d);
      d3 += __shfl_xor(d3, d);
    }
    d0 *= 0.125f; d1 *= 0.125f; d2 *= 0.125f; d3 *= 0.125f;
    float v0 = bf2f(kb[256 + lane]), v1 = bf2f(kb[320 + lane]),
          v2 = bf2f(kb[384 + lane]), v3 = bf2f(kb[448 + lane]);
    float nm, sc, p;
    nm = fmaxf(m0, d0); sc = __expf(m0 - nm); p = __expf(d0 - nm);
    l0 = l0 * sc + p; a0 = fmaf(p, v0, a0 * sc); m0 = nm;
    nm = fmaxf(m1, d1); sc = __expf(m1 - nm); p = __expf(d1 - nm);
    l1 = l1 * sc + p; a1 = fmaf(p, v1, a1 * sc); m1 = nm;
    nm = fmaxf(m2, d2); sc = __expf(m2 - nm); p = __expf(d2 - nm);
    l2 = l2 * sc + p; a2 = fmaf(p, v2, a2 * sc); m2 = nm;
    nm = fmaxf(m3, d3); sc = __expf(m3 - nm); p = __expf(d3 - nm);
    l3 = l3 * sc + p; a3 = fmaf(p, v3, a3 * sc); m3 = nm;
  }
  const float* sb = skipb + (size_t)n * 256;
  float v0 = sb[lane] + ((l0 > 0.f) ? a0 / l0 : 0.f);
  float v1 = sb[64 + lane] + ((l1 > 0.f) ? a1 / l1 : 0.f);
  float v2 = sb[128 + lane] + ((l2 > 0.f) ? a2 / l2 : 0.f);
  float v3 = sb[192 + lane] + ((l3 > 0.f) ? a3 / l3 : 0.f);
  float s1 = wsum(v0 + v1 + v2 + v3);
  float s2 = wsum(v0 * v0 + v1 * v1 + v2 * v2 + v3 * v3);
  float mu = s1 * (1.0f / 256.0f);
  float var = s2 * (1.0f / 256.0f) - mu * mu;
  float rs = rsqrtf(fmaxf(var, 0.0f) + LN_EPS);
  qb[lane] = (v0 - mu) * rs * g[lane] + b[lane];
  qb[64 + lane] = (v1 - mu) * rs * g[64 + lane] + b[64 + lane];
  qb[128 + lane] = (v2 - mu) * rs * g[128 + lane] + b[128 + lane];
  qb[192 + lane] = (v3 - mu) * rs * g[192 + lane] + b[192 + lane];
}

// ---------------- gated residual updates (streaming) ----------------
// P layout per node: [npj(0:64) | pe(64:128) | vn(128:192) | ve(192:256)]
__global__ __launch_bounds__(256) void k_node_update(float* __restrict__ nf, const float* __restrict__ P,
                                                     const float* __restrict__ Sn, const float* __restrict__ bg,
                                                     int N) {
  int i = blockIdx.x * 256 + threadIdx.x;
  if (i >= N * 64) return;
  int n = i >> 6, c = i & 63;
  float g = sigm(Sn[i] + P[(size_t)n * 256 + 128 + c] + bg[c]);
  float npj = P[(size_t)n * 256 + c];
  nf[i] = nf[i] * g + npj * (1.0f - g);
}

__global__ __launch_bounds__(256) void k_edge_update(float* __restrict__ ef, const float* __restrict__ Se,
                                                     const float* __restrict__ P, const int* __restrict__ ei,
                                                     const float* __restrict__ bg, int E) {
  int i = blockIdx.x * 256 + threadIdx.x;
  if (i >= 2 * E * 64) return;
  int e = i >> 6, c = i & 63;
  int s = ei[e];  // src of concatenated edge list == ei[e] for all e in [0,2E)
  float g = sigm(Se[i] + P[(size_t)s * 256 + 192 + c] + bg[c]);
  float epj = P[(size_t)s * 256 + 64 + c];
  ef[i] = ef[i] * g + epj * (1.0f - g);
}

// ---------------- classifier pair kernel ----------------
__global__ __launch_bounds__(256) void k_clf_pair(const float* __restrict__ ABt, const float* __restrict__ ABb,
                                                  const int* __restrict__ ei, const float* __restrict__ bc1,
                                                  const float* __restrict__ Wc2, const float* __restrict__ bc2,
                                                  float* __restrict__ out, int E) {
  int e = blockIdx.x * 4 + (threadIdx.x >> 6);
  int lane = threadIdx.x & 63;
  if (e >= E) return;
  int s = ei[e], t = ei[E + e];
  float h = fmaxf(ABt[(size_t)s * 64 + lane] + ABb[(size_t)t * 64 + lane] + bc1[lane], 0.0f);
  float r = wsum(h * Wc2[lane]);
  if (lane == 0) out[e] = r + bc2[0];
}

// ============================================================================
extern "C" void kernel_launch(void* const* d_in, const int* in_sizes, int n_in,
                              void* d_out, int out_size, void* d_ws, size_t ws_size,
                              hipStream_t stream) {
  const float* x = (const float*)d_in[0];
  const float* edge_attr = (const float*)d_in[1];
  const int* ei = (const int*)d_in[2];
  const int* zk = (const int*)d_in[3];
  const float* z_table = (const float*)d_in[4];
  const float* W_node = (const float*)d_in[5];
  const float* b_node = (const float*)d_in[6];
  const float* W_edge = (const float*)d_in[7];
  const float* b_edge = (const float*)d_in[8];
  const float* cn_w1 = (const float*)d_in[9];
  const float* cn_b1 = (const float*)d_in[10];
  const float* cn_w2 = (const float*)d_in[11];
  const float* cn_b2 = (const float*)d_in[12];
  const float* cn_cw1 = (const float*)d_in[13];
  const float* cn_cb1 = (const float*)d_in[14];
  const float* cn_cw2 = (const float*)d_in[15];
  const float* cn_cb2 = (const float*)d_in[16];
  const float* ce_w1 = (const float*)d_in[17];
  const float* ce_b1 = (const float*)d_in[18];
  const float* ce_w2 = (const float*)d_in[19];
  const float* ce_b2 = (const float*)d_in[20];
  const float* ce_cw1 = (const float*)d_in[21];
  const float* ce_cb1 = (const float*)d_in[22];
  const float* ce_cw2 = (const float*)d_in[23];
  const float* ce_cb2 = (const float*)d_in[24];
  const float* ln_comb_g = (const float*)d_in[25];
  const float* ln_comb_b = (const float*)d_in[26];
  const float* Wq = (const float*)d_in[27];
  const float* bq = (const float*)d_in[28];
  const float* Wk = (const float*)d_in[29];
  const float* bk = (const float*)d_in[30];
  const float* Wv = (const float*)d_in[31];
  const float* bv = (const float*)d_in[32];
  const float* Wskip = (const float*)d_in[33];
  const float* bskip = (const float*)d_in[34];
  const float* ln_tc_g = (const float*)d_in[35];
  const float* ln_tc_b = (const float*)d_in[36];
  const float* Wpn = (const float*)d_in[37];
  const float* bpn = (const float*)d_in[38];
  const float* Wpe = (const float*)d_in[39];
  const float* bpe = (const float*)d_in[40];
  const float* Wg = (const float*)d_in[41];
  const float* bg = (const float*)d_in[42];
  const float* Wc1 = (const float*)d_in[43];
  const float* bc1 = (const float*)d_in[44];
  const float* Wc2 = (const float*)d_in[45];
  const float* bc2 = (const float*)d_in[46];
  float* out = (float*)d_out;

  const int N = in_sizes[0] / 6;   // 50000
  const int E = in_sizes[2] / 2;   // 100000
  const int E2 = 2 * E;

  // ---- workspace carve (~249 MB peak, proven safe in round 2) ----
  char* p = (char*)d_ws;
  auto carve = [&](size_t bytes) -> void* {
    void* r = (void*)p;
    p += (bytes + 255) & ~(size_t)255;
    return r;
  };
  float* qo = (float*)carve((size_t)N * 256 * 4);            // Q -> attn out -> Se / AB
  float* skipb = (float*)carve((size_t)N * 256 * 4);         // skip -> P [npj|pe|vn|ve]
  unsigned short* kvb = (unsigned short*)carve((size_t)N * 512 * 2);  // bf16 K|V -> Sn
  float* ef = (float*)carve((size_t)E2 * 64 * 4);
  float* nf = (float*)carve((size_t)N * 64 * 4);
  float* comb = (float*)carve((size_t)N * 128 * 4);
  float* B2f = (float*)carve((size_t)3 * 256 * 256 * 4);
  float* bias2 = (float*)carve((size_t)3 * 256 * 4);
  int* cnt = (int*)carve((size_t)N * 4);
  int* cur = (int*)carve((size_t)N * 4);
  int* off = (int*)carve((size_t)(N + 1) * 4);
  int* elist = (int*)carve((size_t)E2 * 4);
  float* pm = (float*)carve((size_t)120 * 64 * 4);
  float* ps = (float*)carve((size_t)120 * 64 * 4);
  float* cwv = (float*)carve(64 * 4);
  float* spmax = (float*)carve((size_t)E2 * 4);
  float* spmean = (float*)carve((size_t)E2 * 4);
  float* sconv = (float*)carve((size_t)E2 * 4);
  size_t need = (size_t)(p - (char*)d_ws);

  // aliases (lifetimes verified: P after skip consumed; Se after P produced;
  // Sn after attn consumed kvb; AB after final iteration)
  float* P = skipb;
  float* Se = qo;
  float* Sn = (float*)kvb;
  float* ABt = qo;
  float* ABb = qo + (size_t)N * 64;

  auto cdiv = [](int a, int b) { return (a + b - 1) / b; };

  if (ws_size < need) {
    k_sentinel<<<cdiv(E, 256), 256, 0, stream>>>(out, E);
    return;
  }

  // ---- CSR by dst ----
  k_zero2<<<cdiv(N, 256), 256, 0, stream>>>(cnt, cur, N);
  k_hist<<<cdiv(E2, 256), 256, 0, stream>>>(ei, cnt, E);
  k_scan<<<1, 1024, 0, stream>>>(cnt, off, N);
  k_scatter<<<cdiv(E2, 256), 256, 0, stream>>>(ei, off, cur, elist, E);

  // ---- pack B2ext ----
  const int PACK = 3 * 256 * 256 + 3 * 256;
  k_pack2<<<cdiv(PACK, 256), 256, 0, stream>>>(Wpn, Wpe, bpn, bpe, Wg, B2f, bias2);

  // ---- embeddings ----
  k_node_embed<<<cdiv(N, 4), 256, 0, stream>>>(x, zk, z_table, W_node, b_node, nf, N);
  k_edge_embed<<<cdiv(E2, 4), 256, 0, stream>>>(x, edge_attr, ei, W_edge, b_edge, ef, E);

  // ---- CBAM on nodes then edges ----
  auto run_cbam = [&](float* buf, int rows, const float* w1, const float* b1, const float* w2,
                      const float* b2, const float* cw1, const float* cb1, const float* cw2,
                      const float* cb2) {
    k_pool_partial<<<120, 256, 0, stream>>>(buf, rows, pm, ps);
    k_pool_final<<<1, 128, 0, stream>>>(pm, ps, rows, 120, w1, b1, w2, b2, cwv);
    k_chan_sp<<<cdiv(rows, 4), 256, 0, stream>>>(buf, rows, cwv, spmax, spmean);
    k_conv<<<cdiv(rows, 256), 256, 0, stream>>>(spmax, spmean, rows, cw1, cb1, cw2, cb2, sconv);
    k_row_scale<<<cdiv(rows, 4), 256, 0, stream>>>(buf, rows, sconv);
  };
  run_cbam(nf, N, cn_w1, cn_b1, cn_w2, cn_b2, cn_cw1, cn_cb1, cn_cw2, cn_cb2);
  run_cbam(ef, E2, ce_w1, ce_b1, ce_w2, ce_b2, ce_cw1, ce_cb1, ce_cw2, ce_cb2);

  // ---- T = 3 message-passing iterations ----
  dim3 gq(cdiv(N, 128), 2);   // NC=256
  for (int i = 0; i < 3; ++i) {
    const size_t wof = (size_t)i * 128 * 256;
    const size_t bof = (size_t)i * 256;
    const float* Wg1 = Wg + (size_t)i * 8192;   // rows 0..63 of Wg[i]
    const float* bgi = bg + (size_t)i * 64;
    k_aggcomb<<<cdiv(N, 4), 256, 0, stream>>>(ef, nf, off, elist, comb,
                                              ln_comb_g + (size_t)i * 128, ln_comb_b + (size_t)i * 128, N);
    gemm_tile<0><<<gq, 256, 0, stream>>>(comb, N, 128, Wq + wof, bq + bof, qo, 256, 256);
    gemm_tile<1><<<gq, 256, 0, stream>>>(comb, N, 128, Wk + wof, bk + bof, kvb, 256, 512);
    gemm_tile<1><<<gq, 256, 0, stream>>>(comb, N, 128, Wv + wof, bv + bof, kvb + 256, 256, 512);
    gemm_tile<0><<<gq, 256, 0, stream>>>(comb, N, 128, Wskip + wof, bskip + bof, skipb, 256, 256);
    k_attn<<<cdiv(N, 4), 256, 0, stream>>>(qo, kvb, skipb, off, elist, ei,
                                           ln_tc_g + (size_t)i * 256, ln_tc_b + (size_t)i * 256, N);
    // P = out @ B2ext + bias2ext  -> [npj|pe|vn|ve]  (writes skipb; qo still A)
    gemm_tile<0><<<gq, 256, 0, stream>>>(qo, N, 256, B2f + (size_t)i * 65536,
                                         bias2 + (size_t)i * 256, P, 256, 256);
    // gate logit partials (no shfl): Sn = nf@Wg1 (into kvb), Se = ef@Wg1 (into qo)
    gemm64<<<cdiv(N, 64), 256, 0, stream>>>(nf, N, Wg1, Sn);
    gemm64<<<cdiv(E2, 64), 256, 0, stream>>>(ef, E2, Wg1, Se);
    k_node_update<<<cdiv(N * 64, 256), 256, 0, stream>>>(nf, P, Sn, bgi, N);
    k_edge_update<<<cdiv(E2 * 64, 256), 256, 0, stream>>>(ef, Se, P, ei, bgi, E);
  }

  // ---- classifier: AB halves then pair kernel ----
  gemm64<<<cdiv(N, 64), 256, 0, stream>>>(nf, N, Wc1, ABt);
  gemm64<<<cdiv(N, 64), 256, 0, stream>>>(nf, N, Wc1 + 4096, ABb);
  k_clf_pair<<<cdiv(E, 4), 256, 0, stream>>>(ABt, ABb, ei, bc1, Wc2, bc2, out, E);
  (void)out_size;
  (void)n_in;
}

// Round 4
// 1267.663 us; speedup vs baseline: 2.2562x; 1.8214x over previous
//
#include <hip/hip_runtime.h>

// ============================================================================
// New_LinkNet GNN forward — MFMA bf16 GEMMs + fused gate updates.
// Round-4 changes vs round 3 (2309us, fp32 VALU GEMMs = 82% of time @26TF):
//  - gemm_mfma: bf16 MFMA 128x128-tile GEMM (16x16x32), XOR-swizzled LDS
//      * MODE 0: fused Q|K|V|skip (NC=1024, packed Bt), epilogue splits
//        fp32 Q / bf16 K,V / bf16 skip
//      * MODE 1: P = attn_out @ [Wpn|Wpe|Wpn@Wg2|Wpe@Wg2] (K=256)
//  - gemm_gate: MFMA [M,64]@[64,64] with fused sigmoid-gate epilogue
//    (node/edge updates read P directly; UPD=0 = classifier AB halves)
//  - comb / attn-out / skip stored bf16 (GEMM-A inputs only)
//  - workspace ~239MB (< 249MB proven safe in round 2)
// ============================================================================

#define LN_EPS 1e-5f

typedef __attribute__((ext_vector_type(8))) short bf16x8;
typedef __attribute__((ext_vector_type(4))) float f32x4;

static __device__ __forceinline__ float wsum(float v) {
#pragma unroll
  for (int d = 32; d > 0; d >>= 1) v += __shfl_xor(v, d);
  return v;
}
static __device__ __forceinline__ float sigm(float x) { return 1.0f / (1.0f + __expf(-x)); }
static __device__ __forceinline__ unsigned short f2bf(float f) {
  unsigned int u = __float_as_uint(f);
  u += 0x7FFFu + ((u >> 16) & 1u);
  return (unsigned short)(u >> 16);
}
static __device__ __forceinline__ float bf2f(unsigned short b) {
  return __uint_as_float(((unsigned int)b) << 16);
}

// ---------------- util ----------------
__global__ __launch_bounds__(256) void k_zero2(int* __restrict__ a, int* __restrict__ b, int n) {
  int i = blockIdx.x * 256 + threadIdx.x;
  if (i < n) { a[i] = 0; b[i] = 0; }
}

__global__ __launch_bounds__(256) void k_sentinel(float* __restrict__ out, int n) {
  int i = blockIdx.x * 256 + threadIdx.x;
  if (i < n) out[i] = 1.0e6f;
}

// ---------------- CSR build (by dst) ----------------
__global__ __launch_bounds__(256) void k_hist(const int* __restrict__ ei, int* __restrict__ cnt, int E) {
  int e = blockIdx.x * 256 + threadIdx.x;
  if (e >= 2 * E) return;
  int d = (e < E) ? ei[E + e] : ei[e - E];
  atomicAdd(&cnt[d], 1);
}

__global__ __launch_bounds__(1024) void k_scan(const int* __restrict__ cnt, int* __restrict__ off, int n) {
  __shared__ int buf[1024];
  __shared__ int carry;
  if (threadIdx.x == 0) carry = 0;
  __syncthreads();
  for (int base = 0; base < n; base += 1024) {
    int i = base + (int)threadIdx.x;
    int v = (i < n) ? cnt[i] : 0;
    buf[threadIdx.x] = v;
    __syncthreads();
    for (int d = 1; d < 1024; d <<= 1) {
      int t = (threadIdx.x >= (unsigned)d) ? buf[threadIdx.x - d] : 0;
      __syncthreads();
      buf[threadIdx.x] += t;
      __syncthreads();
    }
    int c0 = carry;
    if (i < n) off[i] = c0 + buf[threadIdx.x] - v;
    __syncthreads();
    if (threadIdx.x == 0) carry = c0 + buf[1023];
    __syncthreads();
  }
  if (threadIdx.x == 0) off[n] = carry;
}

__global__ __launch_bounds__(256) void k_scatter(const int* __restrict__ ei, const int* __restrict__ off,
                                                 int* __restrict__ cur, int* __restrict__ elist, int E) {
  int e = blockIdx.x * 256 + threadIdx.x;
  if (e >= 2 * E) return;
  int d = (e < E) ? ei[E + e] : ei[e - E];
  int pos = atomicAdd(&cur[d], 1);
  elist[off[d] + pos] = e;
}

// ---------------- pack all transposed bf16 weights ----------------
// W1t[3][1024][128], bias1[3][1024], B2t[3][256][256], bias2[3][256],
// Wg1t[3][64][64], Wc1t[2][64][64]
__global__ __launch_bounds__(256) void k_packW(
    const float* __restrict__ Wq, const float* __restrict__ Wk, const float* __restrict__ Wv,
    const float* __restrict__ Ws, const float* __restrict__ bq, const float* __restrict__ bk,
    const float* __restrict__ bv, const float* __restrict__ bs,
    const float* __restrict__ Wpn, const float* __restrict__ Wpe,
    const float* __restrict__ bpn, const float* __restrict__ bpe,
    const float* __restrict__ Wg, const float* __restrict__ Wc1,
    unsigned short* __restrict__ W1t, float* __restrict__ bias1,
    unsigned short* __restrict__ B2t, float* __restrict__ bias2,
    unsigned short* __restrict__ Wg1t, unsigned short* __restrict__ Wc1t) {
  const int S1 = 3 * 1024 * 128, S2 = 3 * 1024, S3 = 3 * 256 * 256, S4 = 3 * 256;
  const int S5 = 3 * 64 * 64, S6 = 2 * 64 * 64;
  int idx = blockIdx.x * 256 + threadIdx.x;
  if (idx < S1) {
    int i = idx / 131072, r = idx % 131072;
    int col = r >> 7, k = r & 127;
    int m = col >> 8, cc = col & 255;
    const float* W = (m == 0) ? Wq : (m == 1) ? Wk : (m == 2) ? Wv : Ws;
    W1t[idx] = f2bf(W[i * 32768 + k * 256 + cc]);
  } else if (idx < S1 + S2) {
    int j = idx - S1;
    int i = j >> 10, col = j & 1023;
    int m = col >> 8, cc = col & 255;
    const float* bsrc = (m == 0) ? bq : (m == 1) ? bk : (m == 2) ? bv : bs;
    bias1[j] = bsrc[i * 256 + cc];
  } else if (idx < S1 + S2 + S3) {
    int j = idx - S1 - S2;
    int i = j / 65536, r = j % 65536;
    int col = r >> 8, k = r & 255;
    float v;
    if (col < 64) v = Wpn[i * 16384 + k * 64 + col];
    else if (col < 128) v = Wpe[i * 16384 + k * 64 + (col - 64)];
    else {
      const float* Wsrc = (col < 192) ? Wpn : Wpe;
      int cc = col & 63;
      float acc = 0.f;
      for (int jj = 0; jj < 64; ++jj)
        acc = fmaf(Wsrc[i * 16384 + k * 64 + jj], Wg[i * 8192 + (64 + jj) * 64 + cc], acc);
      v = acc;
    }
    B2t[j] = f2bf(v);
  } else if (idx < S1 + S2 + S3 + S4) {
    int j = idx - S1 - S2 - S3;
    int i = j >> 8, col = j & 255;
    float v;
    if (col < 64) v = bpn[i * 64 + col];
    else if (col < 128) v = bpe[i * 64 + col - 64];
    else {
      const float* bsrc = (col < 192) ? bpn : bpe;
      int cc = col & 63;
      float acc = 0.f;
      for (int jj = 0; jj < 64; ++jj)
        acc = fmaf(bsrc[i * 64 + jj], Wg[i * 8192 + (64 + jj) * 64 + cc], acc);
      v = acc;
    }
    bias2[j] = v;
  } else if (idx < S1 + S2 + S3 + S4 + S5) {
    int j = idx - S1 - S2 - S3 - S4;
    int i = j / 4096, r = j % 4096;
    int col = r >> 6, k = r & 63;
    Wg1t[j] = f2bf(Wg[i * 8192 + k * 64 + col]);
  } else if (idx < S1 + S2 + S3 + S4 + S5 + S6) {
    int j = idx - S1 - S2 - S3 - S4 - S5;
    int h = j / 4096, r = j % 4096;
    int col = r >> 6, k = r & 63;
    Wc1t[j] = f2bf(Wc1[(h * 64 + k) * 64 + col]);
  }
}

// ---------------- embeddings ----------------
__global__ __launch_bounds__(256) void k_node_embed(
    const float* __restrict__ x, const int* __restrict__ zk, const float* __restrict__ zt,
    const float* __restrict__ Wn, const float* __restrict__ bn, float* __restrict__ nf, int N) {
  int n = blockIdx.x * 4 + (threadIdx.x >> 6);
  int lane = threadIdx.x & 63;
  if (n >= N) return;
  const float* xr = x + (size_t)n * 6;
  float acc = bn[lane];
#pragma unroll
  for (int d = 0; d < 6; ++d) acc = fmaf(xr[d], Wn[d * 64 + lane], acc);
  int zi = __float2int_rn(xr[2]);
  int idx = 0;
#pragma unroll
  for (int t = 5; t >= 0; --t)
    if (zi == zk[t]) idx = t;
  nf[(size_t)n * 64 + lane] = fmaxf(acc, 0.0f) + zt[idx * 64 + lane];
}

__global__ __launch_bounds__(256) void k_edge_embed(
    const float* __restrict__ x, const float* __restrict__ ea, const int* __restrict__ ei,
    const float* __restrict__ We, const float* __restrict__ be, float* __restrict__ ef, int E) {
  int e = blockIdx.x * 4 + (threadIdx.x >> 6);
  int lane = threadIdx.x & 63;
  if (e >= 2 * E) return;
  int e0 = (e < E) ? e : e - E;
  int s = ei[e];
  int d = (e < E) ? ei[E + e] : ei[e - E];
  const float* ar = ea + (size_t)e0 * 4;
  const float* xs = x + (size_t)s * 6;
  const float* xd = x + (size_t)d * 6;
  float in[7];
  in[0] = ar[0]; in[1] = ar[1]; in[2] = ar[2]; in[3] = ar[3];
  in[4] = xs[0] - xd[0]; in[5] = xs[1] - xd[1]; in[6] = xs[2] - xd[2];
  float acc = be[lane];
#pragma unroll
  for (int dd = 0; dd < 7; ++dd) acc = fmaf(in[dd], We[dd * 64 + lane], acc);
  ef[(size_t)e * 64 + lane] = fmaxf(acc, 0.0f);
}

// ---------------- CBAM ----------------
__global__ __launch_bounds__(256) void k_pool_partial(const float* __restrict__ buf, int n,
                                                      float* __restrict__ pm, float* __restrict__ ps) {
  int col = threadIdx.x & 63, rl = threadIdx.x >> 6;
  float mx = -INFINITY, sm = 0.0f;
  for (int r = blockIdx.x * 4 + rl; r < n; r += gridDim.x * 4) {
    float v = buf[(size_t)r * 64 + col];
    mx = fmaxf(mx, v);
    sm += v;
  }
  __shared__ float smx[256], ssm[256];
  smx[threadIdx.x] = mx;
  ssm[threadIdx.x] = sm;
  __syncthreads();
  if (threadIdx.x < 64) {
    int t = threadIdx.x;
    float m2 = fmaxf(fmaxf(smx[t], smx[t + 64]), fmaxf(smx[t + 128], smx[t + 192]));
    float s2 = ssm[t] + ssm[t + 64] + ssm[t + 128] + ssm[t + 192];
    pm[blockIdx.x * 64 + t] = m2;
    ps[blockIdx.x * 64 + t] = s2;
  }
}

__global__ __launch_bounds__(128) void k_pool_final(
    const float* __restrict__ pm, const float* __restrict__ ps, int n, int nblk,
    const float* __restrict__ w1, const float* __restrict__ b1,
    const float* __restrict__ w2, const float* __restrict__ b2, float* __restrict__ cw) {
  __shared__ float cat[128];
  __shared__ float hid[4];
  int t = threadIdx.x;
  if (t < 64) {
    float mx = -INFINITY, sm = 0.0f;
    for (int p = 0; p < nblk; ++p) {
      mx = fmaxf(mx, pm[p * 64 + t]);
      sm += ps[p * 64 + t];
    }
    cat[t] = mx;
    cat[64 + t] = sm / (float)n;
  }
  __syncthreads();
  if (t < 4) {
    float a = b1[t];
    for (int k = 0; k < 128; ++k) a = fmaf(cat[k], w1[k * 4 + t], a);
    hid[t] = fmaxf(a, 0.0f);
  }
  __syncthreads();
  if (t < 64) {
    float a = b2[t];
#pragma unroll
    for (int h = 0; h < 4; ++h) a = fmaf(hid[h], w2[h * 64 + t], a);
    cw[t] = sigm(a);
  }
}

__global__ __launch_bounds__(256) void k_chan_sp(float* __restrict__ buf, int n,
                                                 const float* __restrict__ cw,
                                                 float* __restrict__ spmax, float* __restrict__ spmean) {
  int r = blockIdx.x * 4 + (threadIdx.x >> 6);
  int lane = threadIdx.x & 63;
  if (r >= n) return;
  float v = buf[(size_t)r * 64 + lane] * cw[lane];
  buf[(size_t)r * 64 + lane] = v;
  float mx = v, sm = v;
#pragma unroll
  for (int d = 32; d > 0; d >>= 1) {
    mx = fmaxf(mx, __shfl_xor(mx, d));
    sm += __shfl_xor(sm, d);
  }
  if (lane == 0) {
    spmax[r] = mx;
    spmean[r] = sm * (1.0f / 64.0f);
  }
}

__global__ __launch_bounds__(256) void k_conv(const float* __restrict__ spmax, const float* __restrict__ spmean,
                                              int n, const float* __restrict__ w1, const float* __restrict__ b1,
                                              const float* __restrict__ w2, const float* __restrict__ b2,
                                              float* __restrict__ s) {
  __shared__ float tl[258];
  int base = blockIdx.x * 256;
  for (int q = threadIdx.x; q < 258; q += 256) {
    int p = base - 1 + q;
    float t = 0.0f;
    if (p >= 0 && p < n) {
      float a = b1[0];
#pragma unroll
      for (int h = 0; h < 5; ++h) {
        int pp = p + h - 2;
        if (pp >= 0 && pp < n) a += spmax[pp] * w1[h] + spmean[pp] * w1[5 + h];
      }
      t = fmaxf(a, 0.0f);
    }
    tl[q] = t;
  }
  __syncthreads();
  int o = base + threadIdx.x;
  if (o < n) {
    float a = b2[0] + tl[threadIdx.x] * w2[0] + tl[threadIdx.x + 1] * w2[1] + tl[threadIdx.x + 2] * w2[2];
    s[o] = sigm(a);
  }
}

__global__ __launch_bounds__(256) void k_row_scale(float* __restrict__ buf, int n, const float* __restrict__ s) {
  int r = blockIdx.x * 4 + (threadIdx.x >> 6);
  int lane = threadIdx.x & 63;
  if (r >= n) return;
  buf[(size_t)r * 64 + lane] *= s[r];
}

// ---------------- agg + concat-LN (bf16 out) ----------------
__global__ __launch_bounds__(256) void k_aggcomb(const float* __restrict__ ef, const float* __restrict__ nf,
                                                 const int* __restrict__ off, const int* __restrict__ elist,
                                                 unsigned short* __restrict__ comb, const float* __restrict__ g,
                                                 const float* __restrict__ b, int N) {
  int n = blockIdx.x * 4 + (threadIdx.x >> 6);
  int lane = threadIdx.x & 63;
  if (n >= N) return;
  float agg = 0.0f;
  int i0 = off[n], i1 = off[n + 1];
  for (int idx = i0; idx < i1; ++idx) agg += ef[(size_t)elist[idx] * 64 + lane];
  float y0 = nf[(size_t)n * 64 + lane];
  float y1 = agg - y0;
  float s1 = wsum(y0 + y1);
  float s2 = wsum(y0 * y0 + y1 * y1);
  float mu = s1 * (1.0f / 128.0f);
  float var = s2 * (1.0f / 128.0f) - mu * mu;
  float rs = rsqrtf(fmaxf(var, 0.0f) + LN_EPS);
  comb[(size_t)n * 128 + lane] = f2bf((y0 - mu) * rs * g[lane] + b[lane]);
  comb[(size_t)n * 128 + 64 + lane] = f2bf((y1 - mu) * rs * g[64 + lane] + b[64 + lane]);
}

// ---------------- MFMA GEMM: C[M,NC] = A[M,K](bf16) @ Bt[NC,K](bf16) -------
// MODE 0: NC=1024 fused QKVS epilogue. MODE 1: fp32 out ld=256.
template <int MODE>
__global__ __launch_bounds__(256) void gemm_mfma(
    const unsigned short* __restrict__ A, int M, int K,
    const unsigned short* __restrict__ Bt, const float* __restrict__ bias,
    float* __restrict__ outF, unsigned short* __restrict__ outK,
    unsigned short* __restrict__ outS) {
  __shared__ unsigned short As[128 * 64];
  __shared__ unsigned short Bs[128 * 64];
  const int tid = threadIdx.x;
  const int bm = blockIdx.x * 128;
  const int bn = blockIdx.y * 128;
  const int wid = tid >> 6, lane = tid & 63;
  const int wr = (wid >> 1) * 64, wc = (wid & 1) * 64;
  const int lrow = lane & 15, lkb = (lane >> 4) * 8;
  f32x4 acc[4][4];
#pragma unroll
  for (int m = 0; m < 4; ++m)
#pragma unroll
    for (int n = 0; n < 4; ++n) acc[m][n] = (f32x4){0.f, 0.f, 0.f, 0.f};

  for (int k0 = 0; k0 < K; k0 += 64) {
#pragma unroll
    for (int l = 0; l < 4; ++l) {
      int c = tid + l * 256;
      int row = c >> 3, kc = (c & 7) * 8;
      int sw = row * 64 + (kc ^ ((row & 7) << 3));
      int grow = bm + row;
      bf16x8 v = {0, 0, 0, 0, 0, 0, 0, 0};
      if (grow < M) v = *(const bf16x8*)(A + (size_t)grow * K + k0 + kc);
      *(bf16x8*)&As[sw] = v;
      int gcol = bn + row;
      *(bf16x8*)&Bs[sw] = *(const bf16x8*)(Bt + (size_t)gcol * K + k0 + kc);
    }
    __syncthreads();
#pragma unroll
    for (int ks = 0; ks < 2; ++ks) {
      const int ke = ks * 32 + lkb;
      bf16x8 af[4], bfr[4];
#pragma unroll
      for (int m = 0; m < 4; ++m) {
        int row = wr + m * 16 + lrow;
        af[m] = *(const bf16x8*)&As[row * 64 + (ke ^ ((row & 7) << 3))];
      }
#pragma unroll
      for (int n = 0; n < 4; ++n) {
        int col = wc + n * 16 + lrow;
        bfr[n] = *(const bf16x8*)&Bs[col * 64 + (ke ^ ((col & 7) << 3))];
      }
#pragma unroll
      for (int m = 0; m < 4; ++m)
#pragma unroll
        for (int n = 0; n < 4; ++n)
          acc[m][n] = __builtin_amdgcn_mfma_f32_16x16x32_bf16(af[m], bfr[n], acc[m][n], 0, 0, 0);
    }
    __syncthreads();
  }

  const int colw = lane & 15, rq = (lane >> 4) * 4;
  const int proj = bn >> 8;
#pragma unroll
  for (int m = 0; m < 4; ++m) {
#pragma unroll
    for (int n = 0; n < 4; ++n) {
      int gcol = bn + wc + n * 16 + colw;
      float bv = bias[gcol];
#pragma unroll
      for (int r = 0; r < 4; ++r) {
        int grow = bm + wr + m * 16 + rq + r;
        if (grow >= M) continue;
        float v = acc[m][n][r] + bv;
        if (MODE == 1) {
          outF[(size_t)grow * 256 + gcol] = v;
        } else {
          int cc = gcol & 255;
          if (proj == 0) outF[(size_t)grow * 256 + cc] = v;
          else if (proj == 1) outK[(size_t)grow * 512 + cc] = f2bf(v);
          else if (proj == 2) outK[(size_t)grow * 512 + 256 + cc] = f2bf(v);
          else outS[(size_t)grow * 256 + cc] = f2bf(v);
        }
      }
    }
  }
}

// ------ MFMA [M,64]@[64,64] with fused epilogue ------
// UPD 0: store fp32 C (ld 64). UPD 1: node gate update. UPD 2: edge gate update.
template <int UPD>
__global__ __launch_bounds__(256) void gemm_gate(
    const float* __restrict__ Af, int M, const unsigned short* __restrict__ Wt,
    const float* __restrict__ P, const float* __restrict__ bgv,
    const int* __restrict__ ei, float* __restrict__ upd) {
  __shared__ unsigned short As[128 * 64];
  __shared__ unsigned short Ws[64 * 64];
  const int tid = threadIdx.x;
  const int bm = blockIdx.x * 128;
#pragma unroll
  for (int l = 0; l < 8; ++l) {
    int u = tid + l * 256;
    int row = u >> 4, k4 = (u & 15) << 2;
    int grow = bm + row;
    float4 v = make_float4(0.f, 0.f, 0.f, 0.f);
    if (grow < M) v = *(const float4*)(Af + (size_t)grow * 64 + k4);
    union { unsigned short h[4]; uint2 q; } pk;
    pk.h[0] = f2bf(v.x); pk.h[1] = f2bf(v.y); pk.h[2] = f2bf(v.z); pk.h[3] = f2bf(v.w);
    *(uint2*)&As[row * 64 + (k4 ^ ((row & 7) << 3))] = pk.q;
  }
#pragma unroll
  for (int l = 0; l < 2; ++l) {
    int u = tid + l * 256;
    int row = u >> 3, kc = (u & 7) * 8;
    *(bf16x8*)&Ws[row * 64 + (kc ^ ((row & 7) << 3))] = *(const bf16x8*)(Wt + row * 64 + kc);
  }
  __syncthreads();
  const int wid = tid >> 6, lane = tid & 63;
  const int wr = wid * 32;
  const int lrow = lane & 15, lkb = (lane >> 4) * 8;
  f32x4 acc[2][4];
#pragma unroll
  for (int m = 0; m < 2; ++m)
#pragma unroll
    for (int n = 0; n < 4; ++n) acc[m][n] = (f32x4){0.f, 0.f, 0.f, 0.f};
#pragma unroll
  for (int ks = 0; ks < 2; ++ks) {
    const int ke = ks * 32 + lkb;
    bf16x8 af[2], wf[4];
#pragma unroll
    for (int m = 0; m < 2; ++m) {
      int row = wr + m * 16 + lrow;
      af[m] = *(const bf16x8*)&As[row * 64 + (ke ^ ((row & 7) << 3))];
    }
#pragma unroll
    for (int n = 0; n < 4; ++n) {
      int col = n * 16 + lrow;
      wf[n] = *(const bf16x8*)&Ws[col * 64 + (ke ^ ((col & 7) << 3))];
    }
#pragma unroll
    for (int m = 0; m < 2; ++m)
#pragma unroll
      for (int n = 0; n < 4; ++n)
        acc[m][n] = __builtin_amdgcn_mfma_f32_16x16x32_bf16(af[m], wf[n], acc[m][n], 0, 0, 0);
  }
  const int colw = lane & 15, rq = (lane >> 4) * 4;
#pragma unroll
  for (int m = 0; m < 2; ++m) {
#pragma unroll
    for (int r = 0; r < 4; ++r) {
      int e = bm + wr + m * 16 + rq + r;
      if (e >= M) continue;
      if (UPD == 0) {
#pragma unroll
        for (int n = 0; n < 4; ++n) upd[(size_t)e * 64 + n * 16 + colw] = acc[m][n][r];
      } else {
        int s = (UPD == 2) ? ei[e] : e;
        const float* Pr = P + (size_t)s * 256;
        const int voff = (UPD == 1) ? 128 : 192;
        const int poff = (UPD == 1) ? 0 : 64;
#pragma unroll
        for (int n = 0; n < 4; ++n) {
          int c = n * 16 + colw;
          float g = sigm(acc[m][n][r] + Pr[voff + c] + bgv[c]);
          size_t oi = (size_t)e * 64 + c;
          upd[oi] = upd[oi] * g + Pr[poff + c] * (1.0f - g);
        }
      }
    }
  }
}

// ---------------- attention: per-node wave, online segment softmax + LN ----
__global__ __launch_bounds__(256) void k_attn(const float* __restrict__ qo, const unsigned short* __restrict__ kv,
                                              const unsigned short* __restrict__ skipb, const int* __restrict__ off,
                                              const int* __restrict__ elist, const int* __restrict__ ei,
                                              unsigned short* __restrict__ aob,
                                              const float* __restrict__ g, const float* __restrict__ b, int N) {
  int n = blockIdx.x * 4 + (threadIdx.x >> 6);
  int lane = threadIdx.x & 63;
  if (n >= N) return;
  const float* qb = qo + (size_t)n * 256;
  float q0 = qb[lane], q1 = qb[64 + lane], q2 = qb[128 + lane], q3 = qb[192 + lane];
  float m0 = -INFINITY, m1 = -INFINITY, m2 = -INFINITY, m3 = -INFINITY;
  float l0 = 0.f, l1 = 0.f, l2 = 0.f, l3 = 0.f;
  float a0 = 0.f, a1 = 0.f, a2 = 0.f, a3 = 0.f;
  int i0 = off[n], i1 = off[n + 1];
  for (int idx = i0; idx < i1; ++idx) {
    int eid = elist[idx];
    int s = ei[eid];
    const unsigned short* kb = kv + (size_t)s * 512;
    float d0 = q0 * bf2f(kb[lane]), d1 = q1 * bf2f(kb[64 + lane]),
          d2 = q2 * bf2f(kb[128 + lane]), d3 = q3 * bf2f(kb[192 + lane]);
#pragma unroll
    for (int d = 32; d > 0; d >>= 1) {
      d0 += __shfl_xor(d0, d);
      d1 += __shfl_xor(d1, d);
      d2 += __shfl_xor(d2, d);
      d3 += __shfl_xor(d3, d);
    }
    d0 *= 0.125f; d1 *= 0.125f; d2 *= 0.125f; d3 *= 0.125f;
    float v0 = bf2f(kb[256 + lane]), v1 = bf2f(kb[320 + lane]),
          v2 = bf2f(kb[384 + lane]), v3 = bf2f(kb[448 + lane]);
    float nm, sc, p;
    nm = fmaxf(m0, d0); sc = __expf(m0 - nm); p = __expf(d0 - nm);
    l0 = l0 * sc + p; a0 = fmaf(p, v0, a0 * sc); m0 = nm;
    nm = fmaxf(m1, d1); sc = __expf(m1 - nm); p = __expf(d1 - nm);
    l1 = l1 * sc + p; a1 = fmaf(p, v1, a1 * sc); m1 = nm;
    nm = fmaxf(m2, d2); sc = __expf(m2 - nm); p = __expf(d2 - nm);
    l2 = l2 * sc + p; a2 = fmaf(p, v2, a2 * sc); m2 = nm;
    nm = fmaxf(m3, d3); sc = __expf(m3 - nm); p = __expf(d3 - nm);
    l3 = l3 * sc + p; a3 = fmaf(p, v3, a3 * sc); m3 = nm;
  }
  const unsigned short* sb = skipb + (size_t)n * 256;
  float v0 = bf2f(sb[lane]) + ((l0 > 0.f) ? a0 / l0 : 0.f);
  float v1 = bf2f(sb[64 + lane]) + ((l1 > 0.f) ? a1 / l1 : 0.f);
  float v2 = bf2f(sb[128 + lane]) + ((l2 > 0.f) ? a2 / l2 : 0.f);
  float v3 = bf2f(sb[192 + lane]) + ((l3 > 0.f) ? a3 / l3 : 0.f);
  float s1 = wsum(v0 + v1 + v2 + v3);
  float s2 = wsum(v0 * v0 + v1 * v1 + v2 * v2 + v3 * v3);
  float mu = s1 * (1.0f / 256.0f);
  float var = s2 * (1.0f / 256.0f) - mu * mu;
  float rs = rsqrtf(fmaxf(var, 0.0f) + LN_EPS);
  unsigned short* ab = aob + (size_t)n * 256;
  ab[lane] = f2bf((v0 - mu) * rs * g[lane] + b[lane]);
  ab[64 + lane] = f2bf((v1 - mu) * rs * g[64 + lane] + b[64 + lane]);
  ab[128 + lane] = f2bf((v2 - mu) * rs * g[128 + lane] + b[128 + lane]);
  ab[192 + lane] = f2bf((v3 - mu) * rs * g[192 + lane] + b[192 + lane]);
}

// ---------------- classifier pair kernel ----------------
__global__ __launch_bounds__(256) void k_clf_pair(const float* __restrict__ ABt, const float* __restrict__ ABb,
                                                  const int* __restrict__ ei, const float* __restrict__ bc1,
                                                  const float* __restrict__ Wc2, const float* __restrict__ bc2,
                                                  float* __restrict__ out, int E) {
  int e = blockIdx.x * 4 + (threadIdx.x >> 6);
  int lane = threadIdx.x & 63;
  if (e >= E) return;
  int s = ei[e], t = ei[E + e];
  float h = fmaxf(ABt[(size_t)s * 64 + lane] + ABb[(size_t)t * 64 + lane] + bc1[lane], 0.0f);
  float r = wsum(h * Wc2[lane]);
  if (lane == 0) out[e] = r + bc2[0];
}

// ============================================================================
extern "C" void kernel_launch(void* const* d_in, const int* in_sizes, int n_in,
                              void* d_out, int out_size, void* d_ws, size_t ws_size,
                              hipStream_t stream) {
  const float* x = (const float*)d_in[0];
  const float* edge_attr = (const float*)d_in[1];
  const int* ei = (const int*)d_in[2];
  const int* zk = (const int*)d_in[3];
  const float* z_table = (const float*)d_in[4];
  const float* W_node = (const float*)d_in[5];
  const float* b_node = (const float*)d_in[6];
  const float* W_edge = (const float*)d_in[7];
  const float* b_edge = (const float*)d_in[8];
  const float* cn_w1 = (const float*)d_in[9];
  const float* cn_b1 = (const float*)d_in[10];
  const float* cn_w2 = (const float*)d_in[11];
  const float* cn_b2 = (const float*)d_in[12];
  const float* cn_cw1 = (const float*)d_in[13];
  const float* cn_cb1 = (const float*)d_in[14];
  const float* cn_cw2 = (const float*)d_in[15];
  const float* cn_cb2 = (const float*)d_in[16];
  const float* ce_w1 = (const float*)d_in[17];
  const float* ce_b1 = (const float*)d_in[18];
  const float* ce_w2 = (const float*)d_in[19];
  const float* ce_b2 = (const float*)d_in[20];
  const float* ce_cw1 = (const float*)d_in[21];
  const float* ce_cb1 = (const float*)d_in[22];
  const float* ce_cw2 = (const float*)d_in[23];
  const float* ce_cb2 = (const float*)d_in[24];
  const float* ln_comb_g = (const float*)d_in[25];
  const float* ln_comb_b = (const float*)d_in[26];
  const float* Wq = (const float*)d_in[27];
  const float* bq = (const float*)d_in[28];
  const float* Wk = (const float*)d_in[29];
  const float* bk = (const float*)d_in[30];
  const float* Wv = (const float*)d_in[31];
  const float* bv = (const float*)d_in[32];
  const float* Wskip = (const float*)d_in[33];
  const float* bskip = (const float*)d_in[34];
  const float* ln_tc_g = (const float*)d_in[35];
  const float* ln_tc_b = (const float*)d_in[36];
  const float* Wpn = (const float*)d_in[37];
  const float* bpn = (const float*)d_in[38];
  const float* Wpe = (const float*)d_in[39];
  const float* bpe = (const float*)d_in[40];
  const float* Wg = (const float*)d_in[41];
  const float* bg = (const float*)d_in[42];
  const float* Wc1 = (const float*)d_in[43];
  const float* bc1 = (const float*)d_in[44];
  const float* Wc2 = (const float*)d_in[45];
  const float* bc2 = (const float*)d_in[46];
  float* out = (float*)d_out;

  const int N = in_sizes[0] / 6;   // 50000
  const int E = in_sizes[2] / 2;   // 100000
  const int E2 = 2 * E;

  // ---- workspace carve (~239 MB peak) ----
  char* p = (char*)d_ws;
  auto carve = [&](size_t bytes) -> void* {
    void* r = (void*)p;
    p += (bytes + 255) & ~(size_t)255;
    return r;
  };
  float* qo = (float*)carve((size_t)N * 256 * 4);                      // Q -> P
  unsigned short* skipb = (unsigned short*)carve((size_t)N * 256 * 2); // skip bf16
  unsigned short* kvb = (unsigned short*)carve((size_t)N * 512 * 2);   // K|V bf16
  unsigned short* aob = (unsigned short*)carve((size_t)N * 256 * 2);   // attn out bf16 -> AB f32
  float* ef = (float*)carve((size_t)E2 * 64 * 4);
  float* nf = (float*)carve((size_t)N * 64 * 4);
  unsigned short* comb = (unsigned short*)carve((size_t)N * 128 * 2);
  unsigned short* W1t = (unsigned short*)carve((size_t)3 * 1024 * 128 * 2);
  float* bias1 = (float*)carve((size_t)3 * 1024 * 4);
  unsigned short* B2t = (unsigned short*)carve((size_t)3 * 256 * 256 * 2);
  float* bias2 = (float*)carve((size_t)3 * 256 * 4);
  unsigned short* Wg1t = (unsigned short*)carve((size_t)3 * 64 * 64 * 2);
  unsigned short* Wc1t = (unsigned short*)carve((size_t)2 * 64 * 64 * 2);
  int* cnt = (int*)carve((size_t)N * 4);
  int* cur = (int*)carve((size_t)N * 4);
  int* off = (int*)carve((size_t)(N + 1) * 4);
  int* elist = (int*)carve((size_t)E2 * 4);
  float* pm = (float*)carve((size_t)120 * 64 * 4);
  float* ps = (float*)carve((size_t)120 * 64 * 4);
  float* cwv = (float*)carve(64 * 4);
  float* spmax = (float*)carve((size_t)E2 * 4);
  float* spmean = (float*)carve((size_t)E2 * 4);
  float* sconv = (float*)carve((size_t)E2 * 4);
  size_t need = (size_t)(p - (char*)d_ws);

  float* P = qo;             // P [npj|pe|vn|ve] overwrites Q after attn
  float* ABt = (float*)aob;  // classifier halves reuse aob (dead after last P GEMM)
  float* ABb = (float*)aob + (size_t)N * 64;

  auto cdiv = [](int a, int b) { return (a + b - 1) / b; };

  if (ws_size < need) {
    k_sentinel<<<cdiv(E, 256), 256, 0, stream>>>(out, E);
    return;
  }

  // ---- CSR by dst ----
  k_zero2<<<cdiv(N, 256), 256, 0, stream>>>(cnt, cur, N);
  k_hist<<<cdiv(E2, 256), 256, 0, stream>>>(ei, cnt, E);
  k_scan<<<1, 1024, 0, stream>>>(cnt, off, N);
  k_scatter<<<cdiv(E2, 256), 256, 0, stream>>>(ei, off, cur, elist, E);

  // ---- pack weights (bf16 transposed) ----
  const int PACK = 3 * 1024 * 128 + 3 * 1024 + 3 * 256 * 256 + 3 * 256 + 3 * 64 * 64 + 2 * 64 * 64;
  k_packW<<<cdiv(PACK, 256), 256, 0, stream>>>(Wq, Wk, Wv, Wskip, bq, bk, bv, bskip,
                                               Wpn, Wpe, bpn, bpe, Wg, Wc1,
                                               W1t, bias1, B2t, bias2, Wg1t, Wc1t);

  // ---- embeddings ----
  k_node_embed<<<cdiv(N, 4), 256, 0, stream>>>(x, zk, z_table, W_node, b_node, nf, N);
  k_edge_embed<<<cdiv(E2, 4), 256, 0, stream>>>(x, edge_attr, ei, W_edge, b_edge, ef, E);

  // ---- CBAM on nodes then edges ----
  auto run_cbam = [&](float* buf, int rows, const float* w1, const float* b1, const float* w2,
                      const float* b2, const float* cw1, const float* cb1, const float* cw2,
                      const float* cb2) {
    k_pool_partial<<<120, 256, 0, stream>>>(buf, rows, pm, ps);
    k_pool_final<<<1, 128, 0, stream>>>(pm, ps, rows, 120, w1, b1, w2, b2, cwv);
    k_chan_sp<<<cdiv(rows, 4), 256, 0, stream>>>(buf, rows, cwv, spmax, spmean);
    k_conv<<<cdiv(rows, 256), 256, 0, stream>>>(spmax, spmean, rows, cw1, cb1, cw2, cb2, sconv);
    k_row_scale<<<cdiv(rows, 4), 256, 0, stream>>>(buf, rows, sconv);
  };
  run_cbam(nf, N, cn_w1, cn_b1, cn_w2, cn_b2, cn_cw1, cn_cb1, cn_cw2, cn_cb2);
  run_cbam(ef, E2, ce_w1, ce_b1, ce_w2, ce_b2, ce_cw1, ce_cb1, ce_cw2, ce_cb2);

  // ---- T = 3 message-passing iterations ----
  dim3 gqkvs(cdiv(N, 128), 8);
  dim3 gp(cdiv(N, 128), 2);
  for (int i = 0; i < 3; ++i) {
    k_aggcomb<<<cdiv(N, 4), 256, 0, stream>>>(ef, nf, off, elist, comb,
                                              ln_comb_g + (size_t)i * 128, ln_comb_b + (size_t)i * 128, N);
    gemm_mfma<0><<<gqkvs, 256, 0, stream>>>(comb, N, 128, W1t + (size_t)i * 131072,
                                            bias1 + (size_t)i * 1024, qo, kvb, skipb);
    k_attn<<<cdiv(N, 4), 256, 0, stream>>>(qo, kvb, skipb, off, elist, ei, aob,
                                           ln_tc_g + (size_t)i * 256, ln_tc_b + (size_t)i * 256, N);
    gemm_mfma<1><<<gp, 256, 0, stream>>>(aob, N, 256, B2t + (size_t)i * 65536,
                                         bias2 + (size_t)i * 256, P, nullptr, nullptr);
    gemm_gate<1><<<cdiv(N, 128), 256, 0, stream>>>(nf, N, Wg1t + (size_t)i * 4096, P,
                                                   bg + (size_t)i * 64, nullptr, nf);
    gemm_gate<2><<<cdiv(E2, 128), 256, 0, stream>>>(ef, E2, Wg1t + (size_t)i * 4096, P,
                                                    bg + (size_t)i * 64, ei, ef);
  }

  // ---- classifier ----
  gemm_gate<0><<<cdiv(N, 128), 256, 0, stream>>>(nf, N, Wc1t, nullptr, nullptr, nullptr, ABt);
  gemm_gate<0><<<cdiv(N, 128), 256, 0, stream>>>(nf, N, Wc1t + 4096, nullptr, nullptr, nullptr, ABb);
  k_clf_pair<<<cdiv(E, 4), 256, 0, stream>>>(ABt, ABb, ei, bc1, Wc2, bc2, out, E);
  (void)out_size;
  (void)n_in;
}

// Round 5
// 1079.477 us; speedup vs baseline: 2.6495x; 1.1743x over previous
//
#include <hip/hip_runtime.h>

// ============================================================================
// New_LinkNet GNN forward — MFMA bf16 GEMMs + fused gate updates.
// Round-5 changes vs round 4 (1268us; k_pool_partial 110us latency-bound at
// 120 blocks / scalar loads; k_attn 8 scalar loads + 24 shfl per edge):
//  - CBAM pool/scale kernels vectorized (float4, wave=4rowsx64col) with
//    512-block grids; pool_final parallel-merged over 256 threads.
//  - k_attn lane remap: lane owns (head=l>>4, cols=(l&15)*4..+3) ->
//    Q float4 @4l, K/V uint2 @4l (coalesced), 4 shfl_xor per edge.
//    Buffer layouts unchanged ((l>>4)*64+(l&15)*4 == 4l).
// ============================================================================

#define LN_EPS 1e-5f
#define PBLK 512

typedef __attribute__((ext_vector_type(8))) short bf16x8;
typedef __attribute__((ext_vector_type(4))) float f32x4;

static __device__ __forceinline__ float wsum(float v) {
#pragma unroll
  for (int d = 32; d > 0; d >>= 1) v += __shfl_xor(v, d);
  return v;
}
static __device__ __forceinline__ float sigm(float x) { return 1.0f / (1.0f + __expf(-x)); }
static __device__ __forceinline__ unsigned short f2bf(float f) {
  unsigned int u = __float_as_uint(f);
  u += 0x7FFFu + ((u >> 16) & 1u);
  return (unsigned short)(u >> 16);
}
static __device__ __forceinline__ float bf2f(unsigned short b) {
  return __uint_as_float(((unsigned int)b) << 16);
}

// ---------------- util ----------------
__global__ __launch_bounds__(256) void k_zero2(int* __restrict__ a, int* __restrict__ b, int n) {
  int i = blockIdx.x * 256 + threadIdx.x;
  if (i < n) { a[i] = 0; b[i] = 0; }
}

__global__ __launch_bounds__(256) void k_sentinel(float* __restrict__ out, int n) {
  int i = blockIdx.x * 256 + threadIdx.x;
  if (i < n) out[i] = 1.0e6f;
}

// ---------------- CSR build (by dst) ----------------
__global__ __launch_bounds__(256) void k_hist(const int* __restrict__ ei, int* __restrict__ cnt, int E) {
  int e = blockIdx.x * 256 + threadIdx.x;
  if (e >= 2 * E) return;
  int d = (e < E) ? ei[E + e] : ei[e - E];
  atomicAdd(&cnt[d], 1);
}

__global__ __launch_bounds__(1024) void k_scan(const int* __restrict__ cnt, int* __restrict__ off, int n) {
  __shared__ int buf[1024];
  __shared__ int carry;
  if (threadIdx.x == 0) carry = 0;
  __syncthreads();
  for (int base = 0; base < n; base += 1024) {
    int i = base + (int)threadIdx.x;
    int v = (i < n) ? cnt[i] : 0;
    buf[threadIdx.x] = v;
    __syncthreads();
    for (int d = 1; d < 1024; d <<= 1) {
      int t = (threadIdx.x >= (unsigned)d) ? buf[threadIdx.x - d] : 0;
      __syncthreads();
      buf[threadIdx.x] += t;
      __syncthreads();
    }
    int c0 = carry;
    if (i < n) off[i] = c0 + buf[threadIdx.x] - v;
    __syncthreads();
    if (threadIdx.x == 0) carry = c0 + buf[1023];
    __syncthreads();
  }
  if (threadIdx.x == 0) off[n] = carry;
}

__global__ __launch_bounds__(256) void k_scatter(const int* __restrict__ ei, const int* __restrict__ off,
                                                 int* __restrict__ cur, int* __restrict__ elist, int E) {
  int e = blockIdx.x * 256 + threadIdx.x;
  if (e >= 2 * E) return;
  int d = (e < E) ? ei[E + e] : ei[e - E];
  int pos = atomicAdd(&cur[d], 1);
  elist[off[d] + pos] = e;
}

// ---------------- pack all transposed bf16 weights ----------------
__global__ __launch_bounds__(256) void k_packW(
    const float* __restrict__ Wq, const float* __restrict__ Wk, const float* __restrict__ Wv,
    const float* __restrict__ Ws, const float* __restrict__ bq, const float* __restrict__ bk,
    const float* __restrict__ bv, const float* __restrict__ bs,
    const float* __restrict__ Wpn, const float* __restrict__ Wpe,
    const float* __restrict__ bpn, const float* __restrict__ bpe,
    const float* __restrict__ Wg, const float* __restrict__ Wc1,
    unsigned short* __restrict__ W1t, float* __restrict__ bias1,
    unsigned short* __restrict__ B2t, float* __restrict__ bias2,
    unsigned short* __restrict__ Wg1t, unsigned short* __restrict__ Wc1t) {
  const int S1 = 3 * 1024 * 128, S2 = 3 * 1024, S3 = 3 * 256 * 256, S4 = 3 * 256;
  const int S5 = 3 * 64 * 64, S6 = 2 * 64 * 64;
  int idx = blockIdx.x * 256 + threadIdx.x;
  if (idx < S1) {
    int i = idx / 131072, r = idx % 131072;
    int col = r >> 7, k = r & 127;
    int m = col >> 8, cc = col & 255;
    const float* W = (m == 0) ? Wq : (m == 1) ? Wk : (m == 2) ? Wv : Ws;
    W1t[idx] = f2bf(W[i * 32768 + k * 256 + cc]);
  } else if (idx < S1 + S2) {
    int j = idx - S1;
    int i = j >> 10, col = j & 1023;
    int m = col >> 8, cc = col & 255;
    const float* bsrc = (m == 0) ? bq : (m == 1) ? bk : (m == 2) ? bv : bs;
    bias1[j] = bsrc[i * 256 + cc];
  } else if (idx < S1 + S2 + S3) {
    int j = idx - S1 - S2;
    int i = j / 65536, r = j % 65536;
    int col = r >> 8, k = r & 255;
    float v;
    if (col < 64) v = Wpn[i * 16384 + k * 64 + col];
    else if (col < 128) v = Wpe[i * 16384 + k * 64 + (col - 64)];
    else {
      const float* Wsrc = (col < 192) ? Wpn : Wpe;
      int cc = col & 63;
      float acc = 0.f;
      for (int jj = 0; jj < 64; ++jj)
        acc = fmaf(Wsrc[i * 16384 + k * 64 + jj], Wg[i * 8192 + (64 + jj) * 64 + cc], acc);
      v = acc;
    }
    B2t[j] = f2bf(v);
  } else if (idx < S1 + S2 + S3 + S4) {
    int j = idx - S1 - S2 - S3;
    int i = j >> 8, col = j & 255;
    float v;
    if (col < 64) v = bpn[i * 64 + col];
    else if (col < 128) v = bpe[i * 64 + col - 64];
    else {
      const float* bsrc = (col < 192) ? bpn : bpe;
      int cc = col & 63;
      float acc = 0.f;
      for (int jj = 0; jj < 64; ++jj)
        acc = fmaf(bsrc[i * 64 + jj], Wg[i * 8192 + (64 + jj) * 64 + cc], acc);
      v = acc;
    }
    bias2[j] = v;
  } else if (idx < S1 + S2 + S3 + S4 + S5) {
    int j = idx - S1 - S2 - S3 - S4;
    int i = j / 4096, r = j % 4096;
    int col = r >> 6, k = r & 63;
    Wg1t[j] = f2bf(Wg[i * 8192 + k * 64 + col]);
  } else if (idx < S1 + S2 + S3 + S4 + S5 + S6) {
    int j = idx - S1 - S2 - S3 - S4 - S5;
    int h = j / 4096, r = j % 4096;
    int col = r >> 6, k = r & 63;
    Wc1t[j] = f2bf(Wc1[(h * 64 + k) * 64 + col]);
  }
}

// ---------------- embeddings ----------------
__global__ __launch_bounds__(256) void k_node_embed(
    const float* __restrict__ x, const int* __restrict__ zk, const float* __restrict__ zt,
    const float* __restrict__ Wn, const float* __restrict__ bn, float* __restrict__ nf, int N) {
  int n = blockIdx.x * 4 + (threadIdx.x >> 6);
  int lane = threadIdx.x & 63;
  if (n >= N) return;
  const float* xr = x + (size_t)n * 6;
  float acc = bn[lane];
#pragma unroll
  for (int d = 0; d < 6; ++d) acc = fmaf(xr[d], Wn[d * 64 + lane], acc);
  int zi = __float2int_rn(xr[2]);
  int idx = 0;
#pragma unroll
  for (int t = 5; t >= 0; --t)
    if (zi == zk[t]) idx = t;
  nf[(size_t)n * 64 + lane] = fmaxf(acc, 0.0f) + zt[idx * 64 + lane];
}

__global__ __launch_bounds__(256) void k_edge_embed(
    const float* __restrict__ x, const float* __restrict__ ea, const int* __restrict__ ei,
    const float* __restrict__ We, const float* __restrict__ be, float* __restrict__ ef, int E) {
  int e = blockIdx.x * 4 + (threadIdx.x >> 6);
  int lane = threadIdx.x & 63;
  if (e >= 2 * E) return;
  int e0 = (e < E) ? e : e - E;
  int s = ei[e];
  int d = (e < E) ? ei[E + e] : ei[e - E];
  const float* ar = ea + (size_t)e0 * 4;
  const float* xs = x + (size_t)s * 6;
  const float* xd = x + (size_t)d * 6;
  float in[7];
  in[0] = ar[0]; in[1] = ar[1]; in[2] = ar[2]; in[3] = ar[3];
  in[4] = xs[0] - xd[0]; in[5] = xs[1] - xd[1]; in[6] = xs[2] - xd[2];
  float acc = be[lane];
#pragma unroll
  for (int dd = 0; dd < 7; ++dd) acc = fmaf(in[dd], We[dd * 64 + lane], acc);
  ef[(size_t)e * 64 + lane] = fmaxf(acc, 0.0f);
}

// ---------------- CBAM (vectorized) ----------------
// wave covers 4 rows x 64 cols via float4: lane l -> row sub l>>4, cols (l&15)*4
__global__ __launch_bounds__(256) void k_pool_partial(const float* __restrict__ buf, int n,
                                                      float* __restrict__ pm, float* __restrict__ ps) {
  const int w = threadIdx.x >> 6, l = threadIdx.x & 63;
  const int rsub = l >> 4, c4 = (l & 15) << 2;
  float4 mx = make_float4(-INFINITY, -INFINITY, -INFINITY, -INFINITY);
  float4 sm = make_float4(0.f, 0.f, 0.f, 0.f);
  for (int r = blockIdx.x * 16 + w * 4 + rsub; r < n; r += gridDim.x * 16) {
    float4 v = *(const float4*)(buf + (size_t)r * 64 + c4);
    mx.x = fmaxf(mx.x, v.x); mx.y = fmaxf(mx.y, v.y);
    mx.z = fmaxf(mx.z, v.z); mx.w = fmaxf(mx.w, v.w);
    sm.x += v.x; sm.y += v.y; sm.z += v.z; sm.w += v.w;
  }
#pragma unroll
  for (int d = 16; d < 64; d <<= 1) {
    mx.x = fmaxf(mx.x, __shfl_xor(mx.x, d)); mx.y = fmaxf(mx.y, __shfl_xor(mx.y, d));
    mx.z = fmaxf(mx.z, __shfl_xor(mx.z, d)); mx.w = fmaxf(mx.w, __shfl_xor(mx.w, d));
    sm.x += __shfl_xor(sm.x, d); sm.y += __shfl_xor(sm.y, d);
    sm.z += __shfl_xor(sm.z, d); sm.w += __shfl_xor(sm.w, d);
  }
  __shared__ float smx[4][64], ssm[4][64];
  if (l < 16) {
    *(float4*)&smx[w][c4] = mx;
    *(float4*)&ssm[w][c4] = sm;
  }
  __syncthreads();
  if (threadIdx.x < 64) {
    int t = threadIdx.x;
    float m2 = fmaxf(fmaxf(smx[0][t], smx[1][t]), fmaxf(smx[2][t], smx[3][t]));
    float s2 = ssm[0][t] + ssm[1][t] + ssm[2][t] + ssm[3][t];
    pm[blockIdx.x * 64 + t] = m2;
    ps[blockIdx.x * 64 + t] = s2;
  }
}

__global__ __launch_bounds__(256) void k_pool_final(
    const float* __restrict__ pm, const float* __restrict__ ps, int n, int nblk,
    const float* __restrict__ w1, const float* __restrict__ b1,
    const float* __restrict__ w2, const float* __restrict__ b2, float* __restrict__ cw) {
  __shared__ float redm[4][64], reds[4][64];
  __shared__ float cat[128];
  __shared__ float hid[4];
  int t = threadIdx.x;
  int g = t >> 6, col = t & 63;
  float mx = -INFINITY, sm = 0.0f;
  for (int p = g; p < nblk; p += 4) {
    mx = fmaxf(mx, pm[p * 64 + col]);
    sm += ps[p * 64 + col];
  }
  redm[g][col] = mx;
  reds[g][col] = sm;
  __syncthreads();
  if (t < 64) {
    float m2 = fmaxf(fmaxf(redm[0][t], redm[1][t]), fmaxf(redm[2][t], redm[3][t]));
    float s2 = reds[0][t] + reds[1][t] + reds[2][t] + reds[3][t];
    cat[t] = m2;
    cat[64 + t] = s2 / (float)n;
  }
  __syncthreads();
  if (t < 4) {
    float a = b1[t];
    for (int k = 0; k < 128; ++k) a = fmaf(cat[k], w1[k * 4 + t], a);
    hid[t] = fmaxf(a, 0.0f);
  }
  __syncthreads();
  if (t < 64) {
    float a = b2[t];
#pragma unroll
    for (int h = 0; h < 4; ++h) a = fmaf(hid[h], w2[h * 64 + t], a);
    cw[t] = sigm(a);
  }
}

__global__ __launch_bounds__(256) void k_chan_sp(float* __restrict__ buf, int n,
                                                 const float* __restrict__ cw,
                                                 float* __restrict__ spmax, float* __restrict__ spmean) {
  const int w = threadIdx.x >> 6, l = threadIdx.x & 63;
  const int rsub = l >> 4, c4 = (l & 15) << 2;
  int r = blockIdx.x * 16 + w * 4 + rsub;
  if (r >= n) return;
  float4 cwv = *(const float4*)(cw + c4);
  float4 v = *(const float4*)(buf + (size_t)r * 64 + c4);
  v.x *= cwv.x; v.y *= cwv.y; v.z *= cwv.z; v.w *= cwv.w;
  *(float4*)(buf + (size_t)r * 64 + c4) = v;
  float mx = fmaxf(fmaxf(v.x, v.y), fmaxf(v.z, v.w));
  float sm = v.x + v.y + v.z + v.w;
#pragma unroll
  for (int d = 1; d < 16; d <<= 1) {
    mx = fmaxf(mx, __shfl_xor(mx, d));
    sm += __shfl_xor(sm, d);
  }
  if ((l & 15) == 0) {
    spmax[r] = mx;
    spmean[r] = sm * (1.0f / 64.0f);
  }
}

__global__ __launch_bounds__(256) void k_conv(const float* __restrict__ spmax, const float* __restrict__ spmean,
                                              int n, const float* __restrict__ w1, const float* __restrict__ b1,
                                              const float* __restrict__ w2, const float* __restrict__ b2,
                                              float* __restrict__ s) {
  __shared__ float tl[258];
  int base = blockIdx.x * 256;
  for (int q = threadIdx.x; q < 258; q += 256) {
    int p = base - 1 + q;
    float t = 0.0f;
    if (p >= 0 && p < n) {
      float a = b1[0];
#pragma unroll
      for (int h = 0; h < 5; ++h) {
        int pp = p + h - 2;
        if (pp >= 0 && pp < n) a += spmax[pp] * w1[h] + spmean[pp] * w1[5 + h];
      }
      t = fmaxf(a, 0.0f);
    }
    tl[q] = t;
  }
  __syncthreads();
  int o = base + threadIdx.x;
  if (o < n) {
    float a = b2[0] + tl[threadIdx.x] * w2[0] + tl[threadIdx.x + 1] * w2[1] + tl[threadIdx.x + 2] * w2[2];
    s[o] = sigm(a);
  }
}

__global__ __launch_bounds__(256) void k_row_scale(float* __restrict__ buf, int n, const float* __restrict__ s) {
  int i4 = blockIdx.x * 256 + threadIdx.x;  // float4 index; 16 per row
  if (i4 >= n * 16) return;
  int r = i4 >> 4;
  float sc = s[r];
  float4 v = *(const float4*)(buf + (size_t)i4 * 4);
  v.x *= sc; v.y *= sc; v.z *= sc; v.w *= sc;
  *(float4*)(buf + (size_t)i4 * 4) = v;
}

// ---------------- agg + concat-LN (bf16 out) ----------------
__global__ __launch_bounds__(256) void k_aggcomb(const float* __restrict__ ef, const float* __restrict__ nf,
                                                 const int* __restrict__ off, const int* __restrict__ elist,
                                                 unsigned short* __restrict__ comb, const float* __restrict__ g,
                                                 const float* __restrict__ b, int N) {
  int n = blockIdx.x * 4 + (threadIdx.x >> 6);
  int lane = threadIdx.x & 63;
  if (n >= N) return;
  float agg = 0.0f;
  int i0 = off[n], i1 = off[n + 1];
  for (int idx = i0; idx < i1; ++idx) agg += ef[(size_t)elist[idx] * 64 + lane];
  float y0 = nf[(size_t)n * 64 + lane];
  float y1 = agg - y0;
  float s1 = wsum(y0 + y1);
  float s2 = wsum(y0 * y0 + y1 * y1);
  float mu = s1 * (1.0f / 128.0f);
  float var = s2 * (1.0f / 128.0f) - mu * mu;
  float rs = rsqrtf(fmaxf(var, 0.0f) + LN_EPS);
  comb[(size_t)n * 128 + lane] = f2bf((y0 - mu) * rs * g[lane] + b[lane]);
  comb[(size_t)n * 128 + 64 + lane] = f2bf((y1 - mu) * rs * g[64 + lane] + b[64 + lane]);
}

// ---------------- MFMA GEMM: C[M,NC] = A[M,K](bf16) @ Bt[NC,K](bf16) -------
template <int MODE>
__global__ __launch_bounds__(256) void gemm_mfma(
    const unsigned short* __restrict__ A, int M, int K,
    const unsigned short* __restrict__ Bt, const float* __restrict__ bias,
    float* __restrict__ outF, unsigned short* __restrict__ outK,
    unsigned short* __restrict__ outS) {
  __shared__ unsigned short As[128 * 64];
  __shared__ unsigned short Bs[128 * 64];
  const int tid = threadIdx.x;
  const int bm = blockIdx.x * 128;
  const int bn = blockIdx.y * 128;
  const int wid = tid >> 6, lane = tid & 63;
  const int wr = (wid >> 1) * 64, wc = (wid & 1) * 64;
  const int lrow = lane & 15, lkb = (lane >> 4) * 8;
  f32x4 acc[4][4];
#pragma unroll
  for (int m = 0; m < 4; ++m)
#pragma unroll
    for (int n = 0; n < 4; ++n) acc[m][n] = (f32x4){0.f, 0.f, 0.f, 0.f};

  for (int k0 = 0; k0 < K; k0 += 64) {
#pragma unroll
    for (int l = 0; l < 4; ++l) {
      int c = tid + l * 256;
      int row = c >> 3, kc = (c & 7) * 8;
      int sw = row * 64 + (kc ^ ((row & 7) << 3));
      int grow = bm + row;
      bf16x8 v = {0, 0, 0, 0, 0, 0, 0, 0};
      if (grow < M) v = *(const bf16x8*)(A + (size_t)grow * K + k0 + kc);
      *(bf16x8*)&As[sw] = v;
      int gcol = bn + row;
      *(bf16x8*)&Bs[sw] = *(const bf16x8*)(Bt + (size_t)gcol * K + k0 + kc);
    }
    __syncthreads();
#pragma unroll
    for (int ks = 0; ks < 2; ++ks) {
      const int ke = ks * 32 + lkb;
      bf16x8 af[4], bfr[4];
#pragma unroll
      for (int m = 0; m < 4; ++m) {
        int row = wr + m * 16 + lrow;
        af[m] = *(const bf16x8*)&As[row * 64 + (ke ^ ((row & 7) << 3))];
      }
#pragma unroll
      for (int n = 0; n < 4; ++n) {
        int col = wc + n * 16 + lrow;
        bfr[n] = *(const bf16x8*)&Bs[col * 64 + (ke ^ ((col & 7) << 3))];
      }
#pragma unroll
      for (int m = 0; m < 4; ++m)
#pragma unroll
        for (int n = 0; n < 4; ++n)
          acc[m][n] = __builtin_amdgcn_mfma_f32_16x16x32_bf16(af[m], bfr[n], acc[m][n], 0, 0, 0);
    }
    __syncthreads();
  }

  const int colw = lane & 15, rq = (lane >> 4) * 4;
  const int proj = bn >> 8;
#pragma unroll
  for (int m = 0; m < 4; ++m) {
#pragma unroll
    for (int n = 0; n < 4; ++n) {
      int gcol = bn + wc + n * 16 + colw;
      float bv = bias[gcol];
#pragma unroll
      for (int r = 0; r < 4; ++r) {
        int grow = bm + wr + m * 16 + rq + r;
        if (grow >= M) continue;
        float v = acc[m][n][r] + bv;
        if (MODE == 1) {
          outF[(size_t)grow * 256 + gcol] = v;
        } else {
          int cc = gcol & 255;
          if (proj == 0) outF[(size_t)grow * 256 + cc] = v;
          else if (proj == 1) outK[(size_t)grow * 512 + cc] = f2bf(v);
          else if (proj == 2) outK[(size_t)grow * 512 + 256 + cc] = f2bf(v);
          else outS[(size_t)grow * 256 + cc] = f2bf(v);
        }
      }
    }
  }
}

// ------ MFMA [M,64]@[64,64] with fused epilogue ------
template <int UPD>
__global__ __launch_bounds__(256) void gemm_gate(
    const float* __restrict__ Af, int M, const unsigned short* __restrict__ Wt,
    const float* __restrict__ P, const float* __restrict__ bgv,
    const int* __restrict__ ei, float* __restrict__ upd) {
  __shared__ unsigned short As[128 * 64];
  __shared__ unsigned short Ws[64 * 64];
  const int tid = threadIdx.x;
  const int bm = blockIdx.x * 128;
#pragma unroll
  for (int l = 0; l < 8; ++l) {
    int u = tid + l * 256;
    int row = u >> 4, k4 = (u & 15) << 2;
    int grow = bm + row;
    float4 v = make_float4(0.f, 0.f, 0.f, 0.f);
    if (grow < M) v = *(const float4*)(Af + (size_t)grow * 64 + k4);
    union { unsigned short h[4]; uint2 q; } pk;
    pk.h[0] = f2bf(v.x); pk.h[1] = f2bf(v.y); pk.h[2] = f2bf(v.z); pk.h[3] = f2bf(v.w);
    *(uint2*)&As[row * 64 + (k4 ^ ((row & 7) << 3))] = pk.q;
  }
#pragma unroll
  for (int l = 0; l < 2; ++l) {
    int u = tid + l * 256;
    int row = u >> 3, kc = (u & 7) * 8;
    *(bf16x8*)&Ws[row * 64 + (kc ^ ((row & 7) << 3))] = *(const bf16x8*)(Wt + row * 64 + kc);
  }
  __syncthreads();
  const int wid = tid >> 6, lane = tid & 63;
  const int wr = wid * 32;
  const int lrow = lane & 15, lkb = (lane >> 4) * 8;
  f32x4 acc[2][4];
#pragma unroll
  for (int m = 0; m < 2; ++m)
#pragma unroll
    for (int n = 0; n < 4; ++n) acc[m][n] = (f32x4){0.f, 0.f, 0.f, 0.f};
#pragma unroll
  for (int ks = 0; ks < 2; ++ks) {
    const int ke = ks * 32 + lkb;
    bf16x8 af[2], wf[4];
#pragma unroll
    for (int m = 0; m < 2; ++m) {
      int row = wr + m * 16 + lrow;
      af[m] = *(const bf16x8*)&As[row * 64 + (ke ^ ((row & 7) << 3))];
    }
#pragma unroll
    for (int n = 0; n < 4; ++n) {
      int col = n * 16 + lrow;
      wf[n] = *(const bf16x8*)&Ws[col * 64 + (ke ^ ((col & 7) << 3))];
    }
#pragma unroll
    for (int m = 0; m < 2; ++m)
#pragma unroll
      for (int n = 0; n < 4; ++n)
        acc[m][n] = __builtin_amdgcn_mfma_f32_16x16x32_bf16(af[m], wf[n], acc[m][n], 0, 0, 0);
  }
  const int colw = lane & 15, rq = (lane >> 4) * 4;
#pragma unroll
  for (int m = 0; m < 2; ++m) {
#pragma unroll
    for (int r = 0; r < 4; ++r) {
      int e = bm + wr + m * 16 + rq + r;
      if (e >= M) continue;
      if (UPD == 0) {
#pragma unroll
        for (int n = 0; n < 4; ++n) upd[(size_t)e * 64 + n * 16 + colw] = acc[m][n][r];
      } else {
        int s = (UPD == 2) ? ei[e] : e;
        const float* Pr = P + (size_t)s * 256;
        const int voff = (UPD == 1) ? 128 : 192;
        const int poff = (UPD == 1) ? 0 : 64;
#pragma unroll
        for (int n = 0; n < 4; ++n) {
          int c = n * 16 + colw;
          float g = sigm(acc[m][n][r] + Pr[voff + c] + bgv[c]);
          size_t oi = (size_t)e * 64 + c;
          upd[oi] = upd[oi] * g + Pr[poff + c] * (1.0f - g);
        }
      }
    }
  }
}

// ---------------- attention: lane = (head, 4 cols); wide loads ----------
__global__ __launch_bounds__(256) void k_attn(const float* __restrict__ qo, const unsigned short* __restrict__ kv,
                                              const unsigned short* __restrict__ skipb, const int* __restrict__ off,
                                              const int* __restrict__ elist, const int* __restrict__ ei,
                                              unsigned short* __restrict__ aob,
                                              const float* __restrict__ g, const float* __restrict__ b, int N) {
  int n = blockIdx.x * 4 + (threadIdx.x >> 6);
  int lane = threadIdx.x & 63;
  if (n >= N) return;
  // lane owns head = lane>>4, cols c..c+3 where c=(lane&15)*4; flat offset = 4*lane
  float4 q4 = *(const float4*)(qo + (size_t)n * 256 + 4 * lane);
  float m = -INFINITY, lsum = 0.f;
  float a0 = 0.f, a1 = 0.f, a2 = 0.f, a3 = 0.f;
  int i0 = off[n], i1 = off[n + 1];
  for (int idx = i0; idx < i1; ++idx) {
    int eid = elist[idx];
    int s = ei[eid];
    const unsigned short* kb = kv + (size_t)s * 512;
    union { uint2 u; unsigned short h[4]; } kk, vv;
    kk.u = *(const uint2*)(kb + 4 * lane);
    vv.u = *(const uint2*)(kb + 256 + 4 * lane);
    float d = q4.x * bf2f(kk.h[0]) + q4.y * bf2f(kk.h[1]) + q4.z * bf2f(kk.h[2]) + q4.w * bf2f(kk.h[3]);
#pragma unroll
    for (int dd = 1; dd < 16; dd <<= 1) d += __shfl_xor(d, dd);
    d *= 0.125f;
    float nm = fmaxf(m, d);
    float sc = __expf(m - nm);
    float p = __expf(d - nm);
    lsum = lsum * sc + p;
    a0 = fmaf(p, bf2f(vv.h[0]), a0 * sc);
    a1 = fmaf(p, bf2f(vv.h[1]), a1 * sc);
    a2 = fmaf(p, bf2f(vv.h[2]), a2 * sc);
    a3 = fmaf(p, bf2f(vv.h[3]), a3 * sc);
    m = nm;
  }
  union { uint2 u; unsigned short h[4]; } sb;
  sb.u = *(const uint2*)(skipb + (size_t)n * 256 + 4 * lane);
  float inv = (lsum > 0.f) ? 1.0f / lsum : 0.f;
  float v0 = bf2f(sb.h[0]) + a0 * inv;
  float v1 = bf2f(sb.h[1]) + a1 * inv;
  float v2 = bf2f(sb.h[2]) + a2 * inv;
  float v3 = bf2f(sb.h[3]) + a3 * inv;
  float s1 = wsum(v0 + v1 + v2 + v3);
  float s2 = wsum(v0 * v0 + v1 * v1 + v2 * v2 + v3 * v3);
  float mu = s1 * (1.0f / 256.0f);
  float var = s2 * (1.0f / 256.0f) - mu * mu;
  float rs = rsqrtf(fmaxf(var, 0.0f) + LN_EPS);
  float4 g4 = *(const float4*)(g + 4 * lane);
  float4 b4 = *(const float4*)(b + 4 * lane);
  union { uint2 u; unsigned short h[4]; } ob;
  ob.h[0] = f2bf((v0 - mu) * rs * g4.x + b4.x);
  ob.h[1] = f2bf((v1 - mu) * rs * g4.y + b4.y);
  ob.h[2] = f2bf((v2 - mu) * rs * g4.z + b4.z);
  ob.h[3] = f2bf((v3 - mu) * rs * g4.w + b4.w);
  *(uint2*)(aob + (size_t)n * 256 + 4 * lane) = ob.u;
}

// ---------------- classifier pair kernel ----------------
__global__ __launch_bounds__(256) void k_clf_pair(const float* __restrict__ ABt, const float* __restrict__ ABb,
                                                  const int* __restrict__ ei, const float* __restrict__ bc1,
                                                  const float* __restrict__ Wc2, const float* __restrict__ bc2,
                                                  float* __restrict__ out, int E) {
  int e = blockIdx.x * 4 + (threadIdx.x >> 6);
  int lane = threadIdx.x & 63;
  if (e >= E) return;
  int s = ei[e], t = ei[E + e];
  float h = fmaxf(ABt[(size_t)s * 64 + lane] + ABb[(size_t)t * 64 + lane] + bc1[lane], 0.0f);
  float r = wsum(h * Wc2[lane]);
  if (lane == 0) out[e] = r + bc2[0];
}

// ============================================================================
extern "C" void kernel_launch(void* const* d_in, const int* in_sizes, int n_in,
                              void* d_out, int out_size, void* d_ws, size_t ws_size,
                              hipStream_t stream) {
  const float* x = (const float*)d_in[0];
  const float* edge_attr = (const float*)d_in[1];
  const int* ei = (const int*)d_in[2];
  const int* zk = (const int*)d_in[3];
  const float* z_table = (const float*)d_in[4];
  const float* W_node = (const float*)d_in[5];
  const float* b_node = (const float*)d_in[6];
  const float* W_edge = (const float*)d_in[7];
  const float* b_edge = (const float*)d_in[8];
  const float* cn_w1 = (const float*)d_in[9];
  const float* cn_b1 = (const float*)d_in[10];
  const float* cn_w2 = (const float*)d_in[11];
  const float* cn_b2 = (const float*)d_in[12];
  const float* cn_cw1 = (const float*)d_in[13];
  const float* cn_cb1 = (const float*)d_in[14];
  const float* cn_cw2 = (const float*)d_in[15];
  const float* cn_cb2 = (const float*)d_in[16];
  const float* ce_w1 = (const float*)d_in[17];
  const float* ce_b1 = (const float*)d_in[18];
  const float* ce_w2 = (const float*)d_in[19];
  const float* ce_b2 = (const float*)d_in[20];
  const float* ce_cw1 = (const float*)d_in[21];
  const float* ce_cb1 = (const float*)d_in[22];
  const float* ce_cw2 = (const float*)d_in[23];
  const float* ce_cb2 = (const float*)d_in[24];
  const float* ln_comb_g = (const float*)d_in[25];
  const float* ln_comb_b = (const float*)d_in[26];
  const float* Wq = (const float*)d_in[27];
  const float* bq = (const float*)d_in[28];
  const float* Wk = (const float*)d_in[29];
  const float* bk = (const float*)d_in[30];
  const float* Wv = (const float*)d_in[31];
  const float* bv = (const float*)d_in[32];
  const float* Wskip = (const float*)d_in[33];
  const float* bskip = (const float*)d_in[34];
  const float* ln_tc_g = (const float*)d_in[35];
  const float* ln_tc_b = (const float*)d_in[36];
  const float* Wpn = (const float*)d_in[37];
  const float* bpn = (const float*)d_in[38];
  const float* Wpe = (const float*)d_in[39];
  const float* bpe = (const float*)d_in[40];
  const float* Wg = (const float*)d_in[41];
  const float* bg = (const float*)d_in[42];
  const float* Wc1 = (const float*)d_in[43];
  const float* bc1 = (const float*)d_in[44];
  const float* Wc2 = (const float*)d_in[45];
  const float* bc2 = (const float*)d_in[46];
  float* out = (float*)d_out;

  const int N = in_sizes[0] / 6;   // 50000
  const int E = in_sizes[2] / 2;   // 100000
  const int E2 = 2 * E;

  // ---- workspace carve (~239 MB peak) ----
  char* p = (char*)d_ws;
  auto carve = [&](size_t bytes) -> void* {
    void* r = (void*)p;
    p += (bytes + 255) & ~(size_t)255;
    return r;
  };
  float* qo = (float*)carve((size_t)N * 256 * 4);
  unsigned short* skipb = (unsigned short*)carve((size_t)N * 256 * 2);
  unsigned short* kvb = (unsigned short*)carve((size_t)N * 512 * 2);
  unsigned short* aob = (unsigned short*)carve((size_t)N * 256 * 2);
  float* ef = (float*)carve((size_t)E2 * 64 * 4);
  float* nf = (float*)carve((size_t)N * 64 * 4);
  unsigned short* comb = (unsigned short*)carve((size_t)N * 128 * 2);
  unsigned short* W1t = (unsigned short*)carve((size_t)3 * 1024 * 128 * 2);
  float* bias1 = (float*)carve((size_t)3 * 1024 * 4);
  unsigned short* B2t = (unsigned short*)carve((size_t)3 * 256 * 256 * 2);
  float* bias2 = (float*)carve((size_t)3 * 256 * 4);
  unsigned short* Wg1t = (unsigned short*)carve((size_t)3 * 64 * 64 * 2);
  unsigned short* Wc1t = (unsigned short*)carve((size_t)2 * 64 * 64 * 2);
  int* cnt = (int*)carve((size_t)N * 4);
  int* cur = (int*)carve((size_t)N * 4);
  int* off = (int*)carve((size_t)(N + 1) * 4);
  int* elist = (int*)carve((size_t)E2 * 4);
  float* pm = (float*)carve((size_t)PBLK * 64 * 4);
  float* ps = (float*)carve((size_t)PBLK * 64 * 4);
  float* cwv = (float*)carve(64 * 4);
  float* spmax = (float*)carve((size_t)E2 * 4);
  float* spmean = (float*)carve((size_t)E2 * 4);
  float* sconv = (float*)carve((size_t)E2 * 4);
  size_t need = (size_t)(p - (char*)d_ws);

  float* P = qo;
  float* ABt = (float*)aob;
  float* ABb = (float*)aob + (size_t)N * 64;

  auto cdiv = [](int a, int b) { return (a + b - 1) / b; };

  if (ws_size < need) {
    k_sentinel<<<cdiv(E, 256), 256, 0, stream>>>(out, E);
    return;
  }

  // ---- CSR by dst ----
  k_zero2<<<cdiv(N, 256), 256, 0, stream>>>(cnt, cur, N);
  k_hist<<<cdiv(E2, 256), 256, 0, stream>>>(ei, cnt, E);
  k_scan<<<1, 1024, 0, stream>>>(cnt, off, N);
  k_scatter<<<cdiv(E2, 256), 256, 0, stream>>>(ei, off, cur, elist, E);

  // ---- pack weights (bf16 transposed) ----
  const int PACK = 3 * 1024 * 128 + 3 * 1024 + 3 * 256 * 256 + 3 * 256 + 3 * 64 * 64 + 2 * 64 * 64;
  k_packW<<<cdiv(PACK, 256), 256, 0, stream>>>(Wq, Wk, Wv, Wskip, bq, bk, bv, bskip,
                                               Wpn, Wpe, bpn, bpe, Wg, Wc1,
                                               W1t, bias1, B2t, bias2, Wg1t, Wc1t);

  // ---- embeddings ----
  k_node_embed<<<cdiv(N, 4), 256, 0, stream>>>(x, zk, z_table, W_node, b_node, nf, N);
  k_edge_embed<<<cdiv(E2, 4), 256, 0, stream>>>(x, edge_attr, ei, W_edge, b_edge, ef, E);

  // ---- CBAM on nodes then edges ----
  auto run_cbam = [&](float* buf, int rows, const float* w1, const float* b1, const float* w2,
                      const float* b2, const float* cw1, const float* cb1, const float* cw2,
                      const float* cb2) {
    k_pool_partial<<<PBLK, 256, 0, stream>>>(buf, rows, pm, ps);
    k_pool_final<<<1, 256, 0, stream>>>(pm, ps, rows, PBLK, w1, b1, w2, b2, cwv);
    k_chan_sp<<<cdiv(rows, 16), 256, 0, stream>>>(buf, rows, cwv, spmax, spmean);
    k_conv<<<cdiv(rows, 256), 256, 0, stream>>>(spmax, spmean, rows, cw1, cb1, cw2, cb2, sconv);
    k_row_scale<<<cdiv(rows * 16, 256), 256, 0, stream>>>(buf, rows, sconv);
  };
  run_cbam(nf, N, cn_w1, cn_b1, cn_w2, cn_b2, cn_cw1, cn_cb1, cn_cw2, cn_cb2);
  run_cbam(ef, E2, ce_w1, ce_b1, ce_w2, ce_b2, ce_cw1, ce_cb1, ce_cw2, ce_cb2);

  // ---- T = 3 message-passing iterations ----
  dim3 gqkvs(cdiv(N, 128), 8);
  dim3 gp(cdiv(N, 128), 2);
  for (int i = 0; i < 3; ++i) {
    k_aggcomb<<<cdiv(N, 4), 256, 0, stream>>>(ef, nf, off, elist, comb,
                                              ln_comb_g + (size_t)i * 128, ln_comb_b + (size_t)i * 128, N);
    gemm_mfma<0><<<gqkvs, 256, 0, stream>>>(comb, N, 128, W1t + (size_t)i * 131072,
                                            bias1 + (size_t)i * 1024, qo, kvb, skipb);
    k_attn<<<cdiv(N, 4), 256, 0, stream>>>(qo, kvb, skipb, off, elist, ei, aob,
                                           ln_tc_g + (size_t)i * 256, ln_tc_b + (size_t)i * 256, N);
    gemm_mfma<1><<<gp, 256, 0, stream>>>(aob, N, 256, B2t + (size_t)i * 65536,
                                         bias2 + (size_t)i * 256, P, nullptr, nullptr);
    gemm_gate<1><<<cdiv(N, 128), 256, 0, stream>>>(nf, N, Wg1t + (size_t)i * 4096, P,
                                                   bg + (size_t)i * 64, nullptr, nf);
    gemm_gate<2><<<cdiv(E2, 128), 256, 0, stream>>>(ef, E2, Wg1t + (size_t)i * 4096, P,
                                                    bg + (size_t)i * 64, ei, ef);
  }

  // ---- classifier ----
  gemm_gate<0><<<cdiv(N, 128), 256, 0, stream>>>(nf, N, Wc1t, nullptr, nullptr, nullptr, ABt);
  gemm_gate<0><<<cdiv(N, 128), 256, 0, stream>>>(nf, N, Wc1t + 4096, nullptr, nullptr, nullptr, ABb);
  k_clf_pair<<<cdiv(E, 4), 256, 0, stream>>>(ABt, ABb, ei, bc1, Wc2, bc2, out, E);
  (void)out_size;
  (void)n_in;
}

// Round 6
// 1000.437 us; speedup vs baseline: 2.8588x; 1.0790x over previous
//
#include <hip/hip_runtime.h>

// ============================================================================
// New_LinkNet GNN forward — MFMA bf16 GEMMs + fused gate updates.
// Round-6 changes vs round 5 (1079us; k_scan single-block serial scan 90us,
// occupancy 0.18%):
//  - k_scan replaced by 3-phase multi-block scan (k_scan1/2/3):
//    per-1024-chunk wave scan -> carry-loop over block totals -> add-back.
// Everything else identical to round 5.
// ============================================================================

#define LN_EPS 1e-5f
#define PBLK 512

typedef __attribute__((ext_vector_type(8))) short bf16x8;
typedef __attribute__((ext_vector_type(4))) float f32x4;

static __device__ __forceinline__ float wsum(float v) {
#pragma unroll
  for (int d = 32; d > 0; d >>= 1) v += __shfl_xor(v, d);
  return v;
}
static __device__ __forceinline__ float sigm(float x) { return 1.0f / (1.0f + __expf(-x)); }
static __device__ __forceinline__ unsigned short f2bf(float f) {
  unsigned int u = __float_as_uint(f);
  u += 0x7FFFu + ((u >> 16) & 1u);
  return (unsigned short)(u >> 16);
}
static __device__ __forceinline__ float bf2f(unsigned short b) {
  return __uint_as_float(((unsigned int)b) << 16);
}

// ---------------- util ----------------
__global__ __launch_bounds__(256) void k_zero2(int* __restrict__ a, int* __restrict__ b, int n) {
  int i = blockIdx.x * 256 + threadIdx.x;
  if (i < n) { a[i] = 0; b[i] = 0; }
}

__global__ __launch_bounds__(256) void k_sentinel(float* __restrict__ out, int n) {
  int i = blockIdx.x * 256 + threadIdx.x;
  if (i < n) out[i] = 1.0e6f;
}

// ---------------- CSR build (by dst) ----------------
__global__ __launch_bounds__(256) void k_hist(const int* __restrict__ ei, int* __restrict__ cnt, int E) {
  int e = blockIdx.x * 256 + threadIdx.x;
  if (e >= 2 * E) return;
  int d = (e < E) ? ei[E + e] : ei[e - E];
  atomicAdd(&cnt[d], 1);
}

// Phase 1: block scans 1024 elements (256 thr x 4), writes local-exclusive
// offsets and the block total.
__global__ __launch_bounds__(256) void k_scan1(const int* __restrict__ cnt, int* __restrict__ off,
                                               int* __restrict__ bsum, int n) {
  const int t = threadIdx.x;
  const int lane = t & 63, w = t >> 6;
  const int i0 = blockIdx.x * 1024 + t * 4;
  int v0 = (i0 + 0 < n) ? cnt[i0 + 0] : 0;
  int v1 = (i0 + 1 < n) ? cnt[i0 + 1] : 0;
  int v2 = (i0 + 2 < n) ? cnt[i0 + 2] : 0;
  int v3 = (i0 + 3 < n) ? cnt[i0 + 3] : 0;
  int s = v0 + v1 + v2 + v3;
  int sc = s;
#pragma unroll
  for (int d = 1; d < 64; d <<= 1) {
    int tv = __shfl_up(sc, d);
    if (lane >= d) sc += tv;
  }
  __shared__ int wsums[4];
  if (lane == 63) wsums[w] = sc;
  __syncthreads();
  int wbase = 0;
#pragma unroll
  for (int k = 0; k < 4; ++k)
    if (k < w) wbase += wsums[k];
  int run = wbase + sc - s;  // exclusive base for this thread's 4 elements
  if (i0 + 0 < n) off[i0 + 0] = run; run += v0;
  if (i0 + 1 < n) off[i0 + 1] = run; run += v1;
  if (i0 + 2 < n) off[i0 + 2] = run; run += v2;
  if (i0 + 3 < n) off[i0 + 3] = run;
  if (t == 255) bsum[blockIdx.x] = wbase + sc;  // block total
}

// Phase 2: one wave carry-scans block totals -> boff (exclusive), off[n]=total.
__global__ __launch_bounds__(64) void k_scan2(const int* __restrict__ bsum, int* __restrict__ boff,
                                              int* __restrict__ off, int n, int nblk) {
  const int lane = threadIdx.x;
  int carry = 0;
  for (int base = 0; base < nblk; base += 64) {
    int i = base + lane;
    int v = (i < nblk) ? bsum[i] : 0;
    int sc = v;
#pragma unroll
    for (int d = 1; d < 64; d <<= 1) {
      int tv = __shfl_up(sc, d);
      if (lane >= d) sc += tv;
    }
    if (i < nblk) boff[i] = carry + sc - v;
    carry += __shfl(sc, 63);
  }
  if (lane == 0) off[n] = carry;
}

// Phase 3: add block bases back.
__global__ __launch_bounds__(256) void k_scan3(int* __restrict__ off, const int* __restrict__ boff, int n) {
  int i = blockIdx.x * 256 + threadIdx.x;
  if (i < n) off[i] += boff[i >> 10];
}

__global__ __launch_bounds__(256) void k_scatter(const int* __restrict__ ei, const int* __restrict__ off,
                                                 int* __restrict__ cur, int* __restrict__ elist, int E) {
  int e = blockIdx.x * 256 + threadIdx.x;
  if (e >= 2 * E) return;
  int d = (e < E) ? ei[E + e] : ei[e - E];
  int pos = atomicAdd(&cur[d], 1);
  elist[off[d] + pos] = e;
}

// ---------------- pack all transposed bf16 weights ----------------
__global__ __launch_bounds__(256) void k_packW(
    const float* __restrict__ Wq, const float* __restrict__ Wk, const float* __restrict__ Wv,
    const float* __restrict__ Ws, const float* __restrict__ bq, const float* __restrict__ bk,
    const float* __restrict__ bv, const float* __restrict__ bs,
    const float* __restrict__ Wpn, const float* __restrict__ Wpe,
    const float* __restrict__ bpn, const float* __restrict__ bpe,
    const float* __restrict__ Wg, const float* __restrict__ Wc1,
    unsigned short* __restrict__ W1t, float* __restrict__ bias1,
    unsigned short* __restrict__ B2t, float* __restrict__ bias2,
    unsigned short* __restrict__ Wg1t, unsigned short* __restrict__ Wc1t) {
  const int S1 = 3 * 1024 * 128, S2 = 3 * 1024, S3 = 3 * 256 * 256, S4 = 3 * 256;
  const int S5 = 3 * 64 * 64, S6 = 2 * 64 * 64;
  int idx = blockIdx.x * 256 + threadIdx.x;
  if (idx < S1) {
    int i = idx / 131072, r = idx % 131072;
    int col = r >> 7, k = r & 127;
    int m = col >> 8, cc = col & 255;
    const float* W = (m == 0) ? Wq : (m == 1) ? Wk : (m == 2) ? Wv : Ws;
    W1t[idx] = f2bf(W[i * 32768 + k * 256 + cc]);
  } else if (idx < S1 + S2) {
    int j = idx - S1;
    int i = j >> 10, col = j & 1023;
    int m = col >> 8, cc = col & 255;
    const float* bsrc = (m == 0) ? bq : (m == 1) ? bk : (m == 2) ? bv : bs;
    bias1[j] = bsrc[i * 256 + cc];
  } else if (idx < S1 + S2 + S3) {
    int j = idx - S1 - S2;
    int i = j / 65536, r = j % 65536;
    int col = r >> 8, k = r & 255;
    float v;
    if (col < 64) v = Wpn[i * 16384 + k * 64 + col];
    else if (col < 128) v = Wpe[i * 16384 + k * 64 + (col - 64)];
    else {
      const float* Wsrc = (col < 192) ? Wpn : Wpe;
      int cc = col & 63;
      float acc = 0.f;
      for (int jj = 0; jj < 64; ++jj)
        acc = fmaf(Wsrc[i * 16384 + k * 64 + jj], Wg[i * 8192 + (64 + jj) * 64 + cc], acc);
      v = acc;
    }
    B2t[j] = f2bf(v);
  } else if (idx < S1 + S2 + S3 + S4) {
    int j = idx - S1 - S2 - S3;
    int i = j >> 8, col = j & 255;
    float v;
    if (col < 64) v = bpn[i * 64 + col];
    else if (col < 128) v = bpe[i * 64 + col - 64];
    else {
      const float* bsrc = (col < 192) ? bpn : bpe;
      int cc = col & 63;
      float acc = 0.f;
      for (int jj = 0; jj < 64; ++jj)
        acc = fmaf(bsrc[i * 64 + jj], Wg[i * 8192 + (64 + jj) * 64 + cc], acc);
      v = acc;
    }
    bias2[j] = v;
  } else if (idx < S1 + S2 + S3 + S4 + S5) {
    int j = idx - S1 - S2 - S3 - S4;
    int i = j / 4096, r = j % 4096;
    int col = r >> 6, k = r & 63;
    Wg1t[j] = f2bf(Wg[i * 8192 + k * 64 + col]);
  } else if (idx < S1 + S2 + S3 + S4 + S5 + S6) {
    int j = idx - S1 - S2 - S3 - S4 - S5;
    int h = j / 4096, r = j % 4096;
    int col = r >> 6, k = r & 63;
    Wc1t[j] = f2bf(Wc1[(h * 64 + k) * 64 + col]);
  }
}

// ---------------- embeddings ----------------
__global__ __launch_bounds__(256) void k_node_embed(
    const float* __restrict__ x, const int* __restrict__ zk, const float* __restrict__ zt,
    const float* __restrict__ Wn, const float* __restrict__ bn, float* __restrict__ nf, int N) {
  int n = blockIdx.x * 4 + (threadIdx.x >> 6);
  int lane = threadIdx.x & 63;
  if (n >= N) return;
  const float* xr = x + (size_t)n * 6;
  float acc = bn[lane];
#pragma unroll
  for (int d = 0; d < 6; ++d) acc = fmaf(xr[d], Wn[d * 64 + lane], acc);
  int zi = __float2int_rn(xr[2]);
  int idx = 0;
#pragma unroll
  for (int t = 5; t >= 0; --t)
    if (zi == zk[t]) idx = t;
  nf[(size_t)n * 64 + lane] = fmaxf(acc, 0.0f) + zt[idx * 64 + lane];
}

__global__ __launch_bounds__(256) void k_edge_embed(
    const float* __restrict__ x, const float* __restrict__ ea, const int* __restrict__ ei,
    const float* __restrict__ We, const float* __restrict__ be, float* __restrict__ ef, int E) {
  int e = blockIdx.x * 4 + (threadIdx.x >> 6);
  int lane = threadIdx.x & 63;
  if (e >= 2 * E) return;
  int e0 = (e < E) ? e : e - E;
  int s = ei[e];
  int d = (e < E) ? ei[E + e] : ei[e - E];
  const float* ar = ea + (size_t)e0 * 4;
  const float* xs = x + (size_t)s * 6;
  const float* xd = x + (size_t)d * 6;
  float in[7];
  in[0] = ar[0]; in[1] = ar[1]; in[2] = ar[2]; in[3] = ar[3];
  in[4] = xs[0] - xd[0]; in[5] = xs[1] - xd[1]; in[6] = xs[2] - xd[2];
  float acc = be[lane];
#pragma unroll
  for (int dd = 0; dd < 7; ++dd) acc = fmaf(in[dd], We[dd * 64 + lane], acc);
  ef[(size_t)e * 64 + lane] = fmaxf(acc, 0.0f);
}

// ---------------- CBAM (vectorized) ----------------
__global__ __launch_bounds__(256) void k_pool_partial(const float* __restrict__ buf, int n,
                                                      float* __restrict__ pm, float* __restrict__ ps) {
  const int w = threadIdx.x >> 6, l = threadIdx.x & 63;
  const int rsub = l >> 4, c4 = (l & 15) << 2;
  float4 mx = make_float4(-INFINITY, -INFINITY, -INFINITY, -INFINITY);
  float4 sm = make_float4(0.f, 0.f, 0.f, 0.f);
  for (int r = blockIdx.x * 16 + w * 4 + rsub; r < n; r += gridDim.x * 16) {
    float4 v = *(const float4*)(buf + (size_t)r * 64 + c4);
    mx.x = fmaxf(mx.x, v.x); mx.y = fmaxf(mx.y, v.y);
    mx.z = fmaxf(mx.z, v.z); mx.w = fmaxf(mx.w, v.w);
    sm.x += v.x; sm.y += v.y; sm.z += v.z; sm.w += v.w;
  }
#pragma unroll
  for (int d = 16; d < 64; d <<= 1) {
    mx.x = fmaxf(mx.x, __shfl_xor(mx.x, d)); mx.y = fmaxf(mx.y, __shfl_xor(mx.y, d));
    mx.z = fmaxf(mx.z, __shfl_xor(mx.z, d)); mx.w = fmaxf(mx.w, __shfl_xor(mx.w, d));
    sm.x += __shfl_xor(sm.x, d); sm.y += __shfl_xor(sm.y, d);
    sm.z += __shfl_xor(sm.z, d); sm.w += __shfl_xor(sm.w, d);
  }
  __shared__ float smx[4][64], ssm[4][64];
  if (l < 16) {
    *(float4*)&smx[w][c4] = mx;
    *(float4*)&ssm[w][c4] = sm;
  }
  __syncthreads();
  if (threadIdx.x < 64) {
    int t = threadIdx.x;
    float m2 = fmaxf(fmaxf(smx[0][t], smx[1][t]), fmaxf(smx[2][t], smx[3][t]));
    float s2 = ssm[0][t] + ssm[1][t] + ssm[2][t] + ssm[3][t];
    pm[blockIdx.x * 64 + t] = m2;
    ps[blockIdx.x * 64 + t] = s2;
  }
}

__global__ __launch_bounds__(256) void k_pool_final(
    const float* __restrict__ pm, const float* __restrict__ ps, int n, int nblk,
    const float* __restrict__ w1, const float* __restrict__ b1,
    const float* __restrict__ w2, const float* __restrict__ b2, float* __restrict__ cw) {
  __shared__ float redm[4][64], reds[4][64];
  __shared__ float cat[128];
  __shared__ float hid[4];
  int t = threadIdx.x;
  int g = t >> 6, col = t & 63;
  float mx = -INFINITY, sm = 0.0f;
  for (int p = g; p < nblk; p += 4) {
    mx = fmaxf(mx, pm[p * 64 + col]);
    sm += ps[p * 64 + col];
  }
  redm[g][col] = mx;
  reds[g][col] = sm;
  __syncthreads();
  if (t < 64) {
    float m2 = fmaxf(fmaxf(redm[0][t], redm[1][t]), fmaxf(redm[2][t], redm[3][t]));
    float s2 = reds[0][t] + reds[1][t] + reds[2][t] + reds[3][t];
    cat[t] = m2;
    cat[64 + t] = s2 / (float)n;
  }
  __syncthreads();
  if (t < 4) {
    float a = b1[t];
    for (int k = 0; k < 128; ++k) a = fmaf(cat[k], w1[k * 4 + t], a);
    hid[t] = fmaxf(a, 0.0f);
  }
  __syncthreads();
  if (t < 64) {
    float a = b2[t];
#pragma unroll
    for (int h = 0; h < 4; ++h) a = fmaf(hid[h], w2[h * 64 + t], a);
    cw[t] = sigm(a);
  }
}

__global__ __launch_bounds__(256) void k_chan_sp(float* __restrict__ buf, int n,
                                                 const float* __restrict__ cw,
                                                 float* __restrict__ spmax, float* __restrict__ spmean) {
  const int w = threadIdx.x >> 6, l = threadIdx.x & 63;
  const int rsub = l >> 4, c4 = (l & 15) << 2;
  int r = blockIdx.x * 16 + w * 4 + rsub;
  if (r >= n) return;
  float4 cwv = *(const float4*)(cw + c4);
  float4 v = *(const float4*)(buf + (size_t)r * 64 + c4);
  v.x *= cwv.x; v.y *= cwv.y; v.z *= cwv.z; v.w *= cwv.w;
  *(float4*)(buf + (size_t)r * 64 + c4) = v;
  float mx = fmaxf(fmaxf(v.x, v.y), fmaxf(v.z, v.w));
  float sm = v.x + v.y + v.z + v.w;
#pragma unroll
  for (int d = 1; d < 16; d <<= 1) {
    mx = fmaxf(mx, __shfl_xor(mx, d));
    sm += __shfl_xor(sm, d);
  }
  if ((l & 15) == 0) {
    spmax[r] = mx;
    spmean[r] = sm * (1.0f / 64.0f);
  }
}

__global__ __launch_bounds__(256) void k_conv(const float* __restrict__ spmax, const float* __restrict__ spmean,
                                              int n, const float* __restrict__ w1, const float* __restrict__ b1,
                                              const float* __restrict__ w2, const float* __restrict__ b2,
                                              float* __restrict__ s) {
  __shared__ float tl[258];
  int base = blockIdx.x * 256;
  for (int q = threadIdx.x; q < 258; q += 256) {
    int p = base - 1 + q;
    float t = 0.0f;
    if (p >= 0 && p < n) {
      float a = b1[0];
#pragma unroll
      for (int h = 0; h < 5; ++h) {
        int pp = p + h - 2;
        if (pp >= 0 && pp < n) a += spmax[pp] * w1[h] + spmean[pp] * w1[5 + h];
      }
      t = fmaxf(a, 0.0f);
    }
    tl[q] = t;
  }
  __syncthreads();
  int o = base + threadIdx.x;
  if (o < n) {
    float a = b2[0] + tl[threadIdx.x] * w2[0] + tl[threadIdx.x + 1] * w2[1] + tl[threadIdx.x + 2] * w2[2];
    s[o] = sigm(a);
  }
}

__global__ __launch_bounds__(256) void k_row_scale(float* __restrict__ buf, int n, const float* __restrict__ s) {
  int i4 = blockIdx.x * 256 + threadIdx.x;
  if (i4 >= n * 16) return;
  int r = i4 >> 4;
  float sc = s[r];
  float4 v = *(const float4*)(buf + (size_t)i4 * 4);
  v.x *= sc; v.y *= sc; v.z *= sc; v.w *= sc;
  *(float4*)(buf + (size_t)i4 * 4) = v;
}

// ---------------- agg + concat-LN (bf16 out) ----------------
__global__ __launch_bounds__(256) void k_aggcomb(const float* __restrict__ ef, const float* __restrict__ nf,
                                                 const int* __restrict__ off, const int* __restrict__ elist,
                                                 unsigned short* __restrict__ comb, const float* __restrict__ g,
                                                 const float* __restrict__ b, int N) {
  int n = blockIdx.x * 4 + (threadIdx.x >> 6);
  int lane = threadIdx.x & 63;
  if (n >= N) return;
  float agg = 0.0f;
  int i0 = off[n], i1 = off[n + 1];
  for (int idx = i0; idx < i1; ++idx) agg += ef[(size_t)elist[idx] * 64 + lane];
  float y0 = nf[(size_t)n * 64 + lane];
  float y1 = agg - y0;
  float s1 = wsum(y0 + y1);
  float s2 = wsum(y0 * y0 + y1 * y1);
  float mu = s1 * (1.0f / 128.0f);
  float var = s2 * (1.0f / 128.0f) - mu * mu;
  float rs = rsqrtf(fmaxf(var, 0.0f) + LN_EPS);
  comb[(size_t)n * 128 + lane] = f2bf((y0 - mu) * rs * g[lane] + b[lane]);
  comb[(size_t)n * 128 + 64 + lane] = f2bf((y1 - mu) * rs * g[64 + lane] + b[64 + lane]);
}

// ---------------- MFMA GEMM: C[M,NC] = A[M,K](bf16) @ Bt[NC,K](bf16) -------
template <int MODE>
__global__ __launch_bounds__(256) void gemm_mfma(
    const unsigned short* __restrict__ A, int M, int K,
    const unsigned short* __restrict__ Bt, const float* __restrict__ bias,
    float* __restrict__ outF, unsigned short* __restrict__ outK,
    unsigned short* __restrict__ outS) {
  __shared__ unsigned short As[128 * 64];
  __shared__ unsigned short Bs[128 * 64];
  const int tid = threadIdx.x;
  const int bm = blockIdx.x * 128;
  const int bn = blockIdx.y * 128;
  const int wid = tid >> 6, lane = tid & 63;
  const int wr = (wid >> 1) * 64, wc = (wid & 1) * 64;
  const int lrow = lane & 15, lkb = (lane >> 4) * 8;
  f32x4 acc[4][4];
#pragma unroll
  for (int m = 0; m < 4; ++m)
#pragma unroll
    for (int n = 0; n < 4; ++n) acc[m][n] = (f32x4){0.f, 0.f, 0.f, 0.f};

  for (int k0 = 0; k0 < K; k0 += 64) {
#pragma unroll
    for (int l = 0; l < 4; ++l) {
      int c = tid + l * 256;
      int row = c >> 3, kc = (c & 7) * 8;
      int sw = row * 64 + (kc ^ ((row & 7) << 3));
      int grow = bm + row;
      bf16x8 v = {0, 0, 0, 0, 0, 0, 0, 0};
      if (grow < M) v = *(const bf16x8*)(A + (size_t)grow * K + k0 + kc);
      *(bf16x8*)&As[sw] = v;
      int gcol = bn + row;
      *(bf16x8*)&Bs[sw] = *(const bf16x8*)(Bt + (size_t)gcol * K + k0 + kc);
    }
    __syncthreads();
#pragma unroll
    for (int ks = 0; ks < 2; ++ks) {
      const int ke = ks * 32 + lkb;
      bf16x8 af[4], bfr[4];
#pragma unroll
      for (int m = 0; m < 4; ++m) {
        int row = wr + m * 16 + lrow;
        af[m] = *(const bf16x8*)&As[row * 64 + (ke ^ ((row & 7) << 3))];
      }
#pragma unroll
      for (int n = 0; n < 4; ++n) {
        int col = wc + n * 16 + lrow;
        bfr[n] = *(const bf16x8*)&Bs[col * 64 + (ke ^ ((col & 7) << 3))];
      }
#pragma unroll
      for (int m = 0; m < 4; ++m)
#pragma unroll
        for (int n = 0; n < 4; ++n)
          acc[m][n] = __builtin_amdgcn_mfma_f32_16x16x32_bf16(af[m], bfr[n], acc[m][n], 0, 0, 0);
    }
    __syncthreads();
  }

  const int colw = lane & 15, rq = (lane >> 4) * 4;
  const int proj = bn >> 8;
#pragma unroll
  for (int m = 0; m < 4; ++m) {
#pragma unroll
    for (int n = 0; n < 4; ++n) {
      int gcol = bn + wc + n * 16 + colw;
      float bv = bias[gcol];
#pragma unroll
      for (int r = 0; r < 4; ++r) {
        int grow = bm + wr + m * 16 + rq + r;
        if (grow >= M) continue;
        float v = acc[m][n][r] + bv;
        if (MODE == 1) {
          outF[(size_t)grow * 256 + gcol] = v;
        } else {
          int cc = gcol & 255;
          if (proj == 0) outF[(size_t)grow * 256 + cc] = v;
          else if (proj == 1) outK[(size_t)grow * 512 + cc] = f2bf(v);
          else if (proj == 2) outK[(size_t)grow * 512 + 256 + cc] = f2bf(v);
          else outS[(size_t)grow * 256 + cc] = f2bf(v);
        }
      }
    }
  }
}

// ------ MFMA [M,64]@[64,64] with fused epilogue ------
template <int UPD>
__global__ __launch_bounds__(256) void gemm_gate(
    const float* __restrict__ Af, int M, const unsigned short* __restrict__ Wt,
    const float* __restrict__ P, const float* __restrict__ bgv,
    const int* __restrict__ ei, float* __restrict__ upd) {
  __shared__ unsigned short As[128 * 64];
  __shared__ unsigned short Ws[64 * 64];
  const int tid = threadIdx.x;
  const int bm = blockIdx.x * 128;
#pragma unroll
  for (int l = 0; l < 8; ++l) {
    int u = tid + l * 256;
    int row = u >> 4, k4 = (u & 15) << 2;
    int grow = bm + row;
    float4 v = make_float4(0.f, 0.f, 0.f, 0.f);
    if (grow < M) v = *(const float4*)(Af + (size_t)grow * 64 + k4);
    union { unsigned short h[4]; uint2 q; } pk;
    pk.h[0] = f2bf(v.x); pk.h[1] = f2bf(v.y); pk.h[2] = f2bf(v.z); pk.h[3] = f2bf(v.w);
    *(uint2*)&As[row * 64 + (k4 ^ ((row & 7) << 3))] = pk.q;
  }
#pragma unroll
  for (int l = 0; l < 2; ++l) {
    int u = tid + l * 256;
    int row = u >> 3, kc = (u & 7) * 8;
    *(bf16x8*)&Ws[row * 64 + (kc ^ ((row & 7) << 3))] = *(const bf16x8*)(Wt + row * 64 + kc);
  }
  __syncthreads();
  const int wid = tid >> 6, lane = tid & 63;
  const int wr = wid * 32;
  const int lrow = lane & 15, lkb = (lane >> 4) * 8;
  f32x4 acc[2][4];
#pragma unroll
  for (int m = 0; m < 2; ++m)
#pragma unroll
    for (int n = 0; n < 4; ++n) acc[m][n] = (f32x4){0.f, 0.f, 0.f, 0.f};
#pragma unroll
  for (int ks = 0; ks < 2; ++ks) {
    const int ke = ks * 32 + lkb;
    bf16x8 af[2], wf[4];
#pragma unroll
    for (int m = 0; m < 2; ++m) {
      int row = wr + m * 16 + lrow;
      af[m] = *(const bf16x8*)&As[row * 64 + (ke ^ ((row & 7) << 3))];
    }
#pragma unroll
    for (int n = 0; n < 4; ++n) {
      int col = n * 16 + lrow;
      wf[n] = *(const bf16x8*)&Ws[col * 64 + (ke ^ ((col & 7) << 3))];
    }
#pragma unroll
    for (int m = 0; m < 2; ++m)
#pragma unroll
      for (int n = 0; n < 4; ++n)
        acc[m][n] = __builtin_amdgcn_mfma_f32_16x16x32_bf16(af[m], wf[n], acc[m][n], 0, 0, 0);
  }
  const int colw = lane & 15, rq = (lane >> 4) * 4;
#pragma unroll
  for (int m = 0; m < 2; ++m) {
#pragma unroll
    for (int r = 0; r < 4; ++r) {
      int e = bm + wr + m * 16 + rq + r;
      if (e >= M) continue;
      if (UPD == 0) {
#pragma unroll
        for (int n = 0; n < 4; ++n) upd[(size_t)e * 64 + n * 16 + colw] = acc[m][n][r];
      } else {
        int s = (UPD == 2) ? ei[e] : e;
        const float* Pr = P + (size_t)s * 256;
        const int voff = (UPD == 1) ? 128 : 192;
        const int poff = (UPD == 1) ? 0 : 64;
#pragma unroll
        for (int n = 0; n < 4; ++n) {
          int c = n * 16 + colw;
          float g = sigm(acc[m][n][r] + Pr[voff + c] + bgv[c]);
          size_t oi = (size_t)e * 64 + c;
          upd[oi] = upd[oi] * g + Pr[poff + c] * (1.0f - g);
        }
      }
    }
  }
}

// ---------------- attention: lane = (head, 4 cols); wide loads ----------
__global__ __launch_bounds__(256) void k_attn(const float* __restrict__ qo, const unsigned short* __restrict__ kv,
                                              const unsigned short* __restrict__ skipb, const int* __restrict__ off,
                                              const int* __restrict__ elist, const int* __restrict__ ei,
                                              unsigned short* __restrict__ aob,
                                              const float* __restrict__ g, const float* __restrict__ b, int N) {
  int n = blockIdx.x * 4 + (threadIdx.x >> 6);
  int lane = threadIdx.x & 63;
  if (n >= N) return;
  float4 q4 = *(const float4*)(qo + (size_t)n * 256 + 4 * lane);
  float m = -INFINITY, lsum = 0.f;
  float a0 = 0.f, a1 = 0.f, a2 = 0.f, a3 = 0.f;
  int i0 = off[n], i1 = off[n + 1];
  for (int idx = i0; idx < i1; ++idx) {
    int eid = elist[idx];
    int s = ei[eid];
    const unsigned short* kb = kv + (size_t)s * 512;
    union { uint2 u; unsigned short h[4]; } kk, vv;
    kk.u = *(const uint2*)(kb + 4 * lane);
    vv.u = *(const uint2*)(kb + 256 + 4 * lane);
    float d = q4.x * bf2f(kk.h[0]) + q4.y * bf2f(kk.h[1]) + q4.z * bf2f(kk.h[2]) + q4.w * bf2f(kk.h[3]);
#pragma unroll
    for (int dd = 1; dd < 16; dd <<= 1) d += __shfl_xor(d, dd);
    d *= 0.125f;
    float nm = fmaxf(m, d);
    float sc = __expf(m - nm);
    float p = __expf(d - nm);
    lsum = lsum * sc + p;
    a0 = fmaf(p, bf2f(vv.h[0]), a0 * sc);
    a1 = fmaf(p, bf2f(vv.h[1]), a1 * sc);
    a2 = fmaf(p, bf2f(vv.h[2]), a2 * sc);
    a3 = fmaf(p, bf2f(vv.h[3]), a3 * sc);
    m = nm;
  }
  union { uint2 u; unsigned short h[4]; } sb;
  sb.u = *(const uint2*)(skipb + (size_t)n * 256 + 4 * lane);
  float inv = (lsum > 0.f) ? 1.0f / lsum : 0.f;
  float v0 = bf2f(sb.h[0]) + a0 * inv;
  float v1 = bf2f(sb.h[1]) + a1 * inv;
  float v2 = bf2f(sb.h[2]) + a2 * inv;
  float v3 = bf2f(sb.h[3]) + a3 * inv;
  float s1 = wsum(v0 + v1 + v2 + v3);
  float s2 = wsum(v0 * v0 + v1 * v1 + v2 * v2 + v3 * v3);
  float mu = s1 * (1.0f / 256.0f);
  float var = s2 * (1.0f / 256.0f) - mu * mu;
  float rs = rsqrtf(fmaxf(var, 0.0f) + LN_EPS);
  float4 g4 = *(const float4*)(g + 4 * lane);
  float4 b4 = *(const float4*)(b + 4 * lane);
  union { uint2 u; unsigned short h[4]; } ob;
  ob.h[0] = f2bf((v0 - mu) * rs * g4.x + b4.x);
  ob.h[1] = f2bf((v1 - mu) * rs * g4.y + b4.y);
  ob.h[2] = f2bf((v2 - mu) * rs * g4.z + b4.z);
  ob.h[3] = f2bf((v3 - mu) * rs * g4.w + b4.w);
  *(uint2*)(aob + (size_t)n * 256 + 4 * lane) = ob.u;
}

// ---------------- classifier pair kernel ----------------
__global__ __launch_bounds__(256) void k_clf_pair(const float* __restrict__ ABt, const float* __restrict__ ABb,
                                                  const int* __restrict__ ei, const float* __restrict__ bc1,
                                                  const float* __restrict__ Wc2, const float* __restrict__ bc2,
                                                  float* __restrict__ out, int E) {
  int e = blockIdx.x * 4 + (threadIdx.x >> 6);
  int lane = threadIdx.x & 63;
  if (e >= E) return;
  int s = ei[e], t = ei[E + e];
  float h = fmaxf(ABt[(size_t)s * 64 + lane] + ABb[(size_t)t * 64 + lane] + bc1[lane], 0.0f);
  float r = wsum(h * Wc2[lane]);
  if (lane == 0) out[e] = r + bc2[0];
}

// ============================================================================
extern "C" void kernel_launch(void* const* d_in, const int* in_sizes, int n_in,
                              void* d_out, int out_size, void* d_ws, size_t ws_size,
                              hipStream_t stream) {
  const float* x = (const float*)d_in[0];
  const float* edge_attr = (const float*)d_in[1];
  const int* ei = (const int*)d_in[2];
  const int* zk = (const int*)d_in[3];
  const float* z_table = (const float*)d_in[4];
  const float* W_node = (const float*)d_in[5];
  const float* b_node = (const float*)d_in[6];
  const float* W_edge = (const float*)d_in[7];
  const float* b_edge = (const float*)d_in[8];
  const float* cn_w1 = (const float*)d_in[9];
  const float* cn_b1 = (const float*)d_in[10];
  const float* cn_w2 = (const float*)d_in[11];
  const float* cn_b2 = (const float*)d_in[12];
  const float* cn_cw1 = (const float*)d_in[13];
  const float* cn_cb1 = (const float*)d_in[14];
  const float* cn_cw2 = (const float*)d_in[15];
  const float* cn_cb2 = (const float*)d_in[16];
  const float* ce_w1 = (const float*)d_in[17];
  const float* ce_b1 = (const float*)d_in[18];
  const float* ce_w2 = (const float*)d_in[19];
  const float* ce_b2 = (const float*)d_in[20];
  const float* ce_cw1 = (const float*)d_in[21];
  const float* ce_cb1 = (const float*)d_in[22];
  const float* ce_cw2 = (const float*)d_in[23];
  const float* ce_cb2 = (const float*)d_in[24];
  const float* ln_comb_g = (const float*)d_in[25];
  const float* ln_comb_b = (const float*)d_in[26];
  const float* Wq = (const float*)d_in[27];
  const float* bq = (const float*)d_in[28];
  const float* Wk = (const float*)d_in[29];
  const float* bk = (const float*)d_in[30];
  const float* Wv = (const float*)d_in[31];
  const float* bv = (const float*)d_in[32];
  const float* Wskip = (const float*)d_in[33];
  const float* bskip = (const float*)d_in[34];
  const float* ln_tc_g = (const float*)d_in[35];
  const float* ln_tc_b = (const float*)d_in[36];
  const float* Wpn = (const float*)d_in[37];
  const float* bpn = (const float*)d_in[38];
  const float* Wpe = (const float*)d_in[39];
  const float* bpe = (const float*)d_in[40];
  const float* Wg = (const float*)d_in[41];
  const float* bg = (const float*)d_in[42];
  const float* Wc1 = (const float*)d_in[43];
  const float* bc1 = (const float*)d_in[44];
  const float* Wc2 = (const float*)d_in[45];
  const float* bc2 = (const float*)d_in[46];
  float* out = (float*)d_out;

  const int N = in_sizes[0] / 6;   // 50000
  const int E = in_sizes[2] / 2;   // 100000
  const int E2 = 2 * E;

  // ---- workspace carve (~239 MB peak) ----
  char* p = (char*)d_ws;
  auto carve = [&](size_t bytes) -> void* {
    void* r = (void*)p;
    p += (bytes + 255) & ~(size_t)255;
    return r;
  };
  float* qo = (float*)carve((size_t)N * 256 * 4);
  unsigned short* skipb = (unsigned short*)carve((size_t)N * 256 * 2);
  unsigned short* kvb = (unsigned short*)carve((size_t)N * 512 * 2);
  unsigned short* aob = (unsigned short*)carve((size_t)N * 256 * 2);
  float* ef = (float*)carve((size_t)E2 * 64 * 4);
  float* nf = (float*)carve((size_t)N * 64 * 4);
  unsigned short* comb = (unsigned short*)carve((size_t)N * 128 * 2);
  unsigned short* W1t = (unsigned short*)carve((size_t)3 * 1024 * 128 * 2);
  float* bias1 = (float*)carve((size_t)3 * 1024 * 4);
  unsigned short* B2t = (unsigned short*)carve((size_t)3 * 256 * 256 * 2);
  float* bias2 = (float*)carve((size_t)3 * 256 * 4);
  unsigned short* Wg1t = (unsigned short*)carve((size_t)3 * 64 * 64 * 2);
  unsigned short* Wc1t = (unsigned short*)carve((size_t)2 * 64 * 64 * 2);
  int* cnt = (int*)carve((size_t)N * 4);
  int* cur = (int*)carve((size_t)N * 4);
  int* off = (int*)carve((size_t)(N + 1) * 4);
  int* elist = (int*)carve((size_t)E2 * 4);
  int* bsum = (int*)carve((size_t)256 * 4);
  int* boff = (int*)carve((size_t)256 * 4);
  float* pm = (float*)carve((size_t)PBLK * 64 * 4);
  float* ps = (float*)carve((size_t)PBLK * 64 * 4);
  float* cwv = (float*)carve(64 * 4);
  float* spmax = (float*)carve((size_t)E2 * 4);
  float* spmean = (float*)carve((size_t)E2 * 4);
  float* sconv = (float*)carve((size_t)E2 * 4);
  size_t need = (size_t)(p - (char*)d_ws);

  float* P = qo;
  float* ABt = (float*)aob;
  float* ABb = (float*)aob + (size_t)N * 64;

  auto cdiv = [](int a, int b) { return (a + b - 1) / b; };

  if (ws_size < need) {
    k_sentinel<<<cdiv(E, 256), 256, 0, stream>>>(out, E);
    return;
  }

  // ---- CSR by dst (multi-block scan) ----
  k_zero2<<<cdiv(N, 256), 256, 0, stream>>>(cnt, cur, N);
  k_hist<<<cdiv(E2, 256), 256, 0, stream>>>(ei, cnt, E);
  const int nblk = cdiv(N, 1024);
  k_scan1<<<nblk, 256, 0, stream>>>(cnt, off, bsum, N);
  k_scan2<<<1, 64, 0, stream>>>(bsum, boff, off, N, nblk);
  k_scan3<<<cdiv(N, 256), 256, 0, stream>>>(off, boff, N);
  k_scatter<<<cdiv(E2, 256), 256, 0, stream>>>(ei, off, cur, elist, E);

  // ---- pack weights (bf16 transposed) ----
  const int PACK = 3 * 1024 * 128 + 3 * 1024 + 3 * 256 * 256 + 3 * 256 + 3 * 64 * 64 + 2 * 64 * 64;
  k_packW<<<cdiv(PACK, 256), 256, 0, stream>>>(Wq, Wk, Wv, Wskip, bq, bk, bv, bskip,
                                               Wpn, Wpe, bpn, bpe, Wg, Wc1,
                                               W1t, bias1, B2t, bias2, Wg1t, Wc1t);

  // ---- embeddings ----
  k_node_embed<<<cdiv(N, 4), 256, 0, stream>>>(x, zk, z_table, W_node, b_node, nf, N);
  k_edge_embed<<<cdiv(E2, 4), 256, 0, stream>>>(x, edge_attr, ei, W_edge, b_edge, ef, E);

  // ---- CBAM on nodes then edges ----
  auto run_cbam = [&](float* buf, int rows, const float* w1, const float* b1, const float* w2,
                      const float* b2, const float* cw1, const float* cb1, const float* cw2,
                      const float* cb2) {
    k_pool_partial<<<PBLK, 256, 0, stream>>>(buf, rows, pm, ps);
    k_pool_final<<<1, 256, 0, stream>>>(pm, ps, rows, PBLK, w1, b1, w2, b2, cwv);
    k_chan_sp<<<cdiv(rows, 16), 256, 0, stream>>>(buf, rows, cwv, spmax, spmean);
    k_conv<<<cdiv(rows, 256), 256, 0, stream>>>(spmax, spmean, rows, cw1, cb1, cw2, cb2, sconv);
    k_row_scale<<<cdiv(rows * 16, 256), 256, 0, stream>>>(buf, rows, sconv);
  };
  run_cbam(nf, N, cn_w1, cn_b1, cn_w2, cn_b2, cn_cw1, cn_cb1, cn_cw2, cn_cb2);
  run_cbam(ef, E2, ce_w1, ce_b1, ce_w2, ce_b2, ce_cw1, ce_cb1, ce_cw2, ce_cb2);

  // ---- T = 3 message-passing iterations ----
  dim3 gqkvs(cdiv(N, 128), 8);
  dim3 gp(cdiv(N, 128), 2);
  for (int i = 0; i < 3; ++i) {
    k_aggcomb<<<cdiv(N, 4), 256, 0, stream>>>(ef, nf, off, elist, comb,
                                              ln_comb_g + (size_t)i * 128, ln_comb_b + (size_t)i * 128, N);
    gemm_mfma<0><<<gqkvs, 256, 0, stream>>>(comb, N, 128, W1t + (size_t)i * 131072,
                                            bias1 + (size_t)i * 1024, qo, kvb, skipb);
    k_attn<<<cdiv(N, 4), 256, 0, stream>>>(qo, kvb, skipb, off, elist, ei, aob,
                                           ln_tc_g + (size_t)i * 256, ln_tc_b + (size_t)i * 256, N);
    gemm_mfma<1><<<gp, 256, 0, stream>>>(aob, N, 256, B2t + (size_t)i * 65536,
                                         bias2 + (size_t)i * 256, P, nullptr, nullptr);
    gemm_gate<1><<<cdiv(N, 128), 256, 0, stream>>>(nf, N, Wg1t + (size_t)i * 4096, P,
                                                   bg + (size_t)i * 64, nullptr, nf);
    gemm_gate<2><<<cdiv(E2, 128), 256, 0, stream>>>(ef, E2, Wg1t + (size_t)i * 4096, P,
                                                    bg + (size_t)i * 64, ei, ef);
  }

  // ---- classifier ----
  gemm_gate<0><<<cdiv(N, 128), 256, 0, stream>>>(nf, N, Wc1t, nullptr, nullptr, nullptr, ABt);
  gemm_gate<0><<<cdiv(N, 128), 256, 0, stream>>>(nf, N, Wc1t + 4096, nullptr, nullptr, nullptr, ABb);
  k_clf_pair<<<cdiv(E, 4), 256, 0, stream>>>(ABt, ABb, ei, bc1, Wc2, bc2, out, E);
  (void)out_size;
  (void)n_in;
}